// Round 8
// baseline (300.651 us; speedup 1.0000x reference)
//
#include <hip/hip_runtime.h>
#include <hip/hip_bf16.h>
#include <math.h>
#include <type_traits>

// Round 8: occupancy attack.
//  - gemm_v_res_out: BK=32 double-buffer -> LDS 34.8KB -> 4 blocks/CU (was 2).
//    Swizzle slot = kg ^ ((r>>1)&3) (2-way bank alias = free). vmcnt(4).
//  - tail GEMMs -> 64x64 tiles, grid 512 = 2 blocks/CU (was 256 = 1/CU).
//  - mid_k: t1 on the 64x64 path (512 blocks) + chain (1024 blocks).

typedef __attribute__((ext_vector_type(8))) short short8;
typedef __attribute__((ext_vector_type(4))) float f32x4;
typedef __attribute__((ext_vector_type(4))) float float4v;

#define GLOAD_LDS16(gptr, lptr)                                                 \
    __builtin_amdgcn_global_load_lds(                                           \
        (const __attribute__((address_space(1))) void*)(gptr),                  \
        (__attribute__((address_space(3))) void*)(lptr), 16, 0, 0)

static __device__ __forceinline__ unsigned short f2bf_bits(float v) {
    __hip_bfloat16 h = __float2bfloat16(v);
    return __builtin_bit_cast(unsigned short, h);
}
static __device__ __forceinline__ float bf_bits2f(unsigned short u) {
    return __bfloat162float(__builtin_bit_cast(__hip_bfloat16, u));
}
static __device__ __forceinline__ int swz16(int r, int c16) {
    return (r << 4) + (c16 ^ (r & 7));
}
static __device__ __forceinline__ int swz_elem(int r, int c) {
    return (r << 7) + ((((c << 1) ^ ((r & 7) << 4))) >> 1);
}
static __device__ __forceinline__ int xcd_swz(int bid, int nwg) {
    return (bid & 7) * (nwg >> 3) + (bid >> 3);
}

// ---------------- prep + x-GEMM in one launch ----------------
static __device__ void conv_t_dev(const float* __restrict__ A, const float* __restrict__ Bsub,
                                  __hip_bfloat16* __restrict__ Ot, int K, int N,
                                  int bx, int by, int tid, float* t /* [32][33] */)
{
    const int n0 = bx * 32, k0 = by * 32;
    const int tx = tid & 31, ty = tid >> 5;
    #pragma unroll
    for (int j = 0; j < 4; ++j) {
        int k = k0 + ty + j * 8;
        float v = A[(long)k * N + n0 + tx];
        if (Bsub) v -= Bsub[(long)k * N + n0 + tx];
        t[(ty + j * 8) * 33 + tx] = v;
    }
    __syncthreads();
    #pragma unroll
    for (int j = 0; j < 4; ++j) {
        int n = n0 + ty + j * 8;
        Ot[(long)n * K + k0 + tx] = __float2bfloat16(t[tx * 33 + ty + j * 8]);
    }
}

// x[bm:+128][bn:+128] = features(fp32)[128x64] @ fc1_w(fp32)[64x1024] + fc1_b
static __device__ void xgemm_dev(const float* __restrict__ features,
                                 const float* __restrict__ fc1_w,
                                 const float* __restrict__ fc1_b,
                                 __hip_bfloat16* __restrict__ xb,
                                 int tile, int tid, char* smem)
{
    unsigned short* As = (unsigned short*)smem;            // [128][64] swizzled
    unsigned short* Bs = (unsigned short*)(smem + 16384);  // [128 n][64 k] swizzled
    const int bm = (tile >> 3) << 7, bn = (tile & 7) << 7;
    const int wid = tid >> 6, lane = tid & 63;
    const int wm = (wid >> 1) << 6, wn = (wid & 1) << 6;
    const int l15 = lane & 15, kg = lane >> 4;

    #pragma unroll
    for (int i = 0; i < 8; ++i) {
        int idx = i * 256 + tid;
        int r = idx >> 4, c4 = idx & 15;
        float4v f = *(const float4v*)(features + (long)(bm + r) * 64 + c4 * 4);
        unsigned int p0 = f2bf_bits(f[0]) | ((unsigned int)f2bf_bits(f[1]) << 16);
        unsigned int p1 = f2bf_bits(f[2]) | ((unsigned int)f2bf_bits(f[3]) << 16);
        int dst = r * 64 + (((c4 >> 1) ^ (r & 7)) << 3) + (c4 & 1) * 4;
        unsigned int* p = (unsigned int*)&As[dst];
        p[0] = p0; p[1] = p1;
    }
    #pragma unroll
    for (int i = 0; i < 8; ++i) {
        int idx = i * 256 + tid;
        int k = idx >> 5, c4b = idx & 31;
        float4v g = *(const float4v*)(fc1_w + (long)k * 1024 + bn + c4b * 4);
        #pragma unroll
        for (int q = 0; q < 4; ++q) {
            int n = c4b * 4 + q;
            Bs[n * 64 + (((k >> 3) ^ (n & 7)) << 3) + (k & 7)] = f2bf_bits(g[q]);
        }
    }
    __syncthreads();

    f32x4 acc[4][4] = {};
    #pragma unroll
    for (int ks2 = 0; ks2 < 2; ++ks2) {
        const int kslot = ks2 * 4 + kg;
        short8 af[4], bf_[4];
        #pragma unroll
        for (int m = 0; m < 4; ++m) {
            int r = wm + m * 16 + l15;
            af[m] = *(const short8*)&As[r * 64 + ((kslot ^ (r & 7)) << 3)];
        }
        #pragma unroll
        for (int n = 0; n < 4; ++n) {
            int r = wn + n * 16 + l15;
            bf_[n] = *(const short8*)&Bs[r * 64 + ((kslot ^ (r & 7)) << 3)];
        }
        #pragma unroll
        for (int m = 0; m < 4; ++m)
            #pragma unroll
            for (int n = 0; n < 4; ++n)
                acc[m][n] = __builtin_amdgcn_mfma_f32_16x16x32_bf16(
                    af[m], bf_[n], acc[m][n], 0, 0, 0);
    }
    const int rq = kg << 2;
    #pragma unroll
    for (int n = 0; n < 4; ++n) {
        const int col = bn + wn + n * 16 + l15;
        const float bv = fc1_b[col];
        #pragma unroll
        for (int m = 0; m < 4; ++m)
            #pragma unroll
            for (int j = 0; j < 4; ++j)
                xb[(long)(bm + wm + m * 16 + rq + j) * 1024 + col] =
                    __float2bfloat16(acc[m][n][j] + bv);
    }
}

__global__ __launch_bounds__(256) void prep_x_k(
    const float* __restrict__ features, const float* __restrict__ fc1_w,
    const float* __restrict__ fc1_b, const float* __restrict__ fc2_w,
    const float* __restrict__ fc2_b, const float* __restrict__ g1_w,
    const float* __restrict__ g2_w, const float* __restrict__ wq,
    const float* __restrict__ wk, const float* __restrict__ wv,
    const float* __restrict__ wq2, const float* __restrict__ wk2,
    const float* __restrict__ gg1_w, const float* __restrict__ gg2_w,
    __hip_bfloat16* __restrict__ fc2T, __hip_bfloat16* __restrict__ wdT,
    __hip_bfloat16* __restrict__ wvT, __hip_bfloat16* __restrict__ g1T,
    __hip_bfloat16* __restrict__ g2T, __hip_bfloat16* __restrict__ wd2T,
    __hip_bfloat16* __restrict__ gg1T, __hip_bfloat16* __restrict__ gg2T,
    __hip_bfloat16* __restrict__ xb, float* __restrict__ invde,
    float* __restrict__ out)
{
    __shared__ __align__(16) char smem[32768];
    float* t = (float*)smem;
    const int bid = blockIdx.x;
    const int tid = threadIdx.x;

    if (bid == 0) {
        #pragma unroll
        for (int i = 0; i < 2; ++i) {
            int idx = tid + i * 256;
            invde[idx] = exp2f(-9.96578428466209f * (float)idx * (1.f / 512.f));
        }
    } else if (bid < 257) {               // out = features + fc2_b
        const float4v* f4 = (const float4v*)features;
        float4v* o4 = (float4v*)out;
        const float4v* b4 = (const float4v*)fc2_b;
        long base = (long)(bid - 1) * 1024;
        #pragma unroll
        for (int i = 0; i < 4; ++i) {
            long idx = base + tid + i * 256;
            o4[idx] = f4[idx] + b4[idx & 15];
        }
    } else if (bid < 1281) {              // wdT = (wq - wk)^T
        int tt = bid - 257;  conv_t_dev(wq, wk, wdT, 1024, 1024, tt & 31, tt >> 5, tid, t);
    } else if (bid < 2305) {              // wvT
        int tt = bid - 1281; conv_t_dev(wv, nullptr, wvT, 1024, 1024, tt & 31, tt >> 5, tid, t);
    } else if (bid < 3329) {              // g1T
        int tt = bid - 2305; conv_t_dev(g1_w, nullptr, g1T, 1024, 1024, tt & 31, tt >> 5, tid, t);
    } else if (bid < 4353) {              // g2T
        int tt = bid - 3329; conv_t_dev(g2_w, nullptr, g2T, 1024, 1024, tt & 31, tt >> 5, tid, t);
    } else if (bid < 4417) {              // fc2T (K=1024, N=64)
        int tt = bid - 4353; conv_t_dev(fc2_w, nullptr, fc2T, 1024, 64, tt & 1, tt >> 1, tid, t);
    } else if (bid < 4433) {              // wd2T
        int tt = bid - 4417; conv_t_dev(wq2, wk2, wd2T, 128, 128, tt & 3, tt >> 2, tid, t);
    } else if (bid < 4449) {              // gg1T
        int tt = bid - 4433; conv_t_dev(gg1_w, nullptr, gg1T, 128, 128, tt & 3, tt >> 2, tid, t);
    } else if (bid < 4465) {              // gg2T
        int tt = bid - 4449; conv_t_dev(gg2_w, nullptr, gg2T, 128, 128, tt & 3, tt >> 2, tid, t);
    } else {                              // x-GEMM tiles (1024)
        xgemm_dev(features, fc1_w, fc1_b, xb, bid - 4465, tid, smem);
    }
}

// ------- 64x64 GEMM, BK=32, counted-vmcnt double-buffer (2 blocks/CU) -------
// grid nwg = 16 * (M/64). A rows bm, Bt rows bn. K=1024 fixed strides.
template <int OP, bool CS>
static __device__ void gemm6464_dev(
    const __hip_bfloat16* __restrict__ A, const __hip_bfloat16* __restrict__ Bt,
    const float* __restrict__ bias, __hip_bfloat16* __restrict__ Co,
    float scale, float* __restrict__ pcs, int swz, int tid, char* smem)
{
    const int wid = tid >> 6, lane = tid & 63;
    const int bm = (swz >> 4) << 6, bn = (swz & 15) << 6;
    const int wm = (wid >> 1) << 5, wn = (wid & 1) << 5;
    f32x4 acc[2][2] = {};
    const int l15 = lane & 15, kg = lane >> 4;
    const int rS = tid >> 2;
    const int c4s = (tid & 3) ^ ((rS >> 1) & 3);

#define G66_STAGE(b, k0)                                                        \
    { char* base = smem + (b) * 8192;                                           \
      GLOAD_LDS16(A + (long)(bm + rS) * 1024 + (k0) + c4s * 8,                  \
                  base + (wid << 6) * 16);                                      \
      GLOAD_LDS16(Bt + (long)(bn + rS) * 1024 + (k0) + c4s * 8,                 \
                  base + 4096 + (wid << 6) * 16); }

    G66_STAGE(0, 0);
    #pragma unroll 2
    for (int kt = 0; kt < 32; ++kt) {
        if (kt < 31) {
            G66_STAGE((kt + 1) & 1, (kt + 1) * 32);
            asm volatile("s_waitcnt vmcnt(2)" ::: "memory");
        } else {
            asm volatile("s_waitcnt vmcnt(0)" ::: "memory");
        }
        __builtin_amdgcn_s_barrier();
        __builtin_amdgcn_sched_barrier(0);
        const char* AsB = smem + (kt & 1) * 8192;
        const char* BsB = AsB + 4096;
        short8 af[2], bf_[2];
        #pragma unroll
        for (int m = 0; m < 2; ++m) {
            const int R = wm + m * 16 + l15;
            af[m] = *(const short8*)(AsB + R * 64 + ((kg ^ ((R >> 1) & 3)) << 4));
        }
        #pragma unroll
        for (int n = 0; n < 2; ++n) {
            const int R = wn + n * 16 + l15;
            bf_[n] = *(const short8*)(BsB + R * 64 + ((kg ^ ((R >> 1) & 3)) << 4));
        }
        __builtin_amdgcn_s_setprio(1);
        #pragma unroll
        for (int m = 0; m < 2; ++m)
            #pragma unroll
            for (int n = 0; n < 2; ++n)
                acc[m][n] = __builtin_amdgcn_mfma_f32_16x16x32_bf16(
                    af[m], bf_[n], acc[m][n], 0, 0, 0);
        __builtin_amdgcn_s_setprio(0);
        __builtin_amdgcn_s_barrier();
    }
#undef G66_STAGE

    const int rq = kg << 2;
    float csum[2];
    #pragma unroll
    for (int n = 0; n < 2; ++n) {
        const int col = bn + wn + n * 16 + l15;
        const float bv = bias ? bias[col] : 0.f;
        csum[n] = 0.f;
        #pragma unroll
        for (int m = 0; m < 2; ++m) {
            #pragma unroll
            for (int j = 0; j < 4; ++j) {
                const int row = bm + wm + m * 16 + rq + j;
                float cv = acc[m][n][j] + bv;
                if (OP == 1) cv = fmaxf(cv, 0.f);
                if (OP == 2) cv = __expf(cv * scale);
                if (CS) csum[n] += cv;
                Co[(long)row * 1024 + col] = __float2bfloat16(cv);
            }
        }
    }
    if (CS) {
        __syncthreads();
        float* ps = (float*)smem;  // [64 col][8 slot] = 2 KB
        const int slot = ((wid >> 1) << 2) | kg;
        #pragma unroll
        for (int n = 0; n < 2; ++n)
            ps[(wn + n * 16 + l15) * 8 + slot] = csum[n];
        __syncthreads();
        if (tid < 64) {
            float s = 0.f;
            #pragma unroll
            for (int q = 0; q < 8; ++q) s += ps[tid * 8 + q];
            pcs[(long)(swz >> 4) * 1024 + bn + tid] = s;
        }
    }
}

template <int OP, bool CS>
__global__ __launch_bounds__(256) void gemm6464_k(
    const __hip_bfloat16* __restrict__ A, const __hip_bfloat16* __restrict__ Bt,
    const float* __restrict__ bias, __hip_bfloat16* __restrict__ Co,
    float scale, float* __restrict__ pcs)
{
    __shared__ __align__(16) char smem[16384];
    const int swz = xcd_swz(blockIdx.y * gridDim.x + blockIdx.x, gridDim.x * gridDim.y);
    gemm6464_dev<OP, CS>(A, Bt, bias, Co, scale, pcs, swz, threadIdx.x, smem);
}

// ---------------- fused group-MLP chain (device fn, unchanged) ----------------
static __device__ void chain_dev(
    const __hip_bfloat16* __restrict__ xb,
    const __hip_bfloat16* __restrict__ w1T,
    const __hip_bfloat16* __restrict__ w2T,
    const __hip_bfloat16* __restrict__ w3T,
    const float* __restrict__ b2, const float* __restrict__ b3,
    __hip_bfloat16* __restrict__ e1, float* __restrict__ pcs1,
    int tileIdx, int tid, char* smem)
{
    unsigned short* act = (unsigned short*)smem;
    unsigned short* Wb  = (unsigned short*)(smem + 32768);
    const int wid = tid >> 6, lane = tid & 63;
    const int wm = (wid >> 1) << 6, wn = (wid & 1) << 6;
    const long tile = (long)tileIdx * (128 * 128);

    #pragma unroll
    for (int i = 0; i < 8; ++i) {
        int L = i * 256 + wid * 64 + lane;
        int r = L >> 4, c16o = (L & 15) ^ (r & 7);
        GLOAD_LDS16(xb + tile + r * 128 + c16o * 8,
                    (char*)act + (i * 256 + wid * 64) * 16);
        GLOAD_LDS16(w1T + r * 128 + c16o * 8,
                    (char*)Wb + (i * 256 + wid * 64) * 16);
    }
    __syncthreads();

    f32x4 acc[4][4];
    const int rq = (lane >> 4) << 2;

#define CHAIN_ZERO()                                                            \
    _Pragma("unroll") for (int m = 0; m < 4; ++m)                               \
        _Pragma("unroll") for (int n = 0; n < 4; ++n)                           \
            acc[m][n] = (f32x4){0.f, 0.f, 0.f, 0.f};

#define CHAIN_MM()                                                              \
    _Pragma("unroll") for (int ks = 0; ks < 4; ++ks) {                          \
        short8 af[4], bfv[4];                                                   \
        const int kc = ks * 4 + (lane >> 4);                                    \
        _Pragma("unroll") for (int m = 0; m < 4; ++m) {                         \
            int r = wm + m * 16 + (lane & 15);                                  \
            af[m] = *(const short8*)((const char*)act + swz16(r, kc) * 16);     \
        }                                                                       \
        _Pragma("unroll") for (int n = 0; n < 4; ++n) {                         \
            int r = wn + n * 16 + (lane & 15);                                  \
            bfv[n] = *(const short8*)((const char*)Wb + swz16(r, kc) * 16);     \
        }                                                                       \
        _Pragma("unroll") for (int m = 0; m < 4; ++m)                           \
            _Pragma("unroll") for (int n = 0; n < 4; ++n)                       \
                acc[m][n] = __builtin_amdgcn_mfma_f32_16x16x32_bf16(            \
                    af[m], bfv[n], acc[m][n], 0, 0, 0);                         \
    }

#define STAGE_W(wptr)                                                           \
    _Pragma("unroll") for (int i = 0; i < 8; ++i) {                             \
        int L = i * 256 + wid * 64 + lane;                                      \
        int r = L >> 4, c16o = (L & 15) ^ (r & 7);                              \
        GLOAD_LDS16((wptr) + r * 128 + c16o * 8,                                \
                    (char*)Wb + (i * 256 + wid * 64) * 16);                     \
    }

    CHAIN_ZERO(); CHAIN_MM();
    __syncthreads();
    STAGE_W(w2T);
    #pragma unroll
    for (int m = 0; m < 4; ++m)
        #pragma unroll
        for (int n = 0; n < 4; ++n)
            #pragma unroll
            for (int j = 0; j < 4; ++j) {
                int row = wm + m * 16 + rq + j, col = wn + n * 16 + (lane & 15);
                act[swz_elem(row, col)] = f2bf_bits(acc[m][n][j]);
            }
    __syncthreads();

    CHAIN_ZERO(); CHAIN_MM();
    __syncthreads();
    STAGE_W(w3T);
    {
        float bv[4];
        #pragma unroll
        for (int n = 0; n < 4; ++n) bv[n] = b2[wn + n * 16 + (lane & 15)];
        #pragma unroll
        for (int m = 0; m < 4; ++m)
            #pragma unroll
            for (int n = 0; n < 4; ++n)
                #pragma unroll
                for (int j = 0; j < 4; ++j) {
                    int row = wm + m * 16 + rq + j, col = wn + n * 16 + (lane & 15);
                    act[swz_elem(row, col)] = f2bf_bits(fmaxf(acc[m][n][j] + bv[n], 0.f));
                }
    }
    __syncthreads();

    CHAIN_ZERO(); CHAIN_MM();
    __syncthreads();
    {
        float bv[4];
        #pragma unroll
        for (int n = 0; n < 4; ++n) bv[n] = b3[wn + n * 16 + (lane & 15)];
        #pragma unroll
        for (int m = 0; m < 4; ++m)
            #pragma unroll
            for (int n = 0; n < 4; ++n)
                #pragma unroll
                for (int j = 0; j < 4; ++j) {
                    int row = wm + m * 16 + rq + j, col = wn + n * 16 + (lane & 15);
                    float ev = __expf((acc[m][n][j] + bv[n]) * 0.08838834764831845f);
                    act[swz_elem(row, col)] = f2bf_bits(ev);
                }
    }
    __syncthreads();

    #pragma unroll
    for (int i = 0; i < 8; ++i) {
        int idx = i * 256 + tid;
        int r = idx >> 4, c16o = idx & 15;
        short8 vd = *(const short8*)((const char*)act + swz16(r, c16o) * 16);
        *(short8*)((__hip_bfloat16*)e1 + tile + r * 128 + c16o * 8) = vd;
    }
    #pragma unroll
    for (int i = 0; i < 4; ++i) {
        int p = i * 256 + tid;
        int g = p >> 7, c = p & 127;
        float s = 0.f;
        #pragma unroll
        for (int t16 = 0; t16 < 16; ++t16) {
            int r = t16 * 8 + g;
            s += bf_bits2f(act[swz_elem(r, c)]);
        }
        pcs1[(long)tileIdx * 1024 + p] = s;
    }
#undef CHAIN_ZERO
#undef CHAIN_MM
#undef STAGE_W
}

// mid: blocks 0..511 = tail GEMM 1 (d2 = gf2 @ wd), 512..1535 = chain tiles
__global__ __launch_bounds__(256) void mid_k(
    const __hip_bfloat16* __restrict__ xb, const __hip_bfloat16* __restrict__ wdT,
    __hip_bfloat16* __restrict__ d2b,
    const __hip_bfloat16* __restrict__ wd2T, const __hip_bfloat16* __restrict__ gg1T,
    const __hip_bfloat16* __restrict__ gg2T, const float* __restrict__ gg1_b,
    const float* __restrict__ gg2_b, __hip_bfloat16* __restrict__ e1,
    float* __restrict__ pcs1)
{
    __shared__ __align__(16) char smem[65536];
    const int bid = blockIdx.x, tid = threadIdx.x;
    if (bid < 512) {
        gemm6464_dev<0, false>(xb + (size_t)14336 * 1024, wdT, nullptr, d2b,
                               0.f, nullptr, xcd_swz(bid, 512), tid, smem);
    } else {
        chain_dev(xb, wd2T, gg1T, gg2T, gg1_b, gg2_b, e1, pcs1, bid - 512, tid, smem);
    }
}

// reduce: blocks 0-15 -> rcs1, 16-31 -> rcs2
__global__ __launch_bounds__(1024) void reduce_k(
    const float* __restrict__ pcs1, const float* __restrict__ pcs2,
    float* __restrict__ rcs1, float* __restrict__ rcs2)
{
    __shared__ float red[16][64];
    const int tx = threadIdx.x, ty = threadIdx.y;
    if (blockIdx.x < 16) {
        const int col = blockIdx.x * 64 + tx;
        float s = 0.f;
        for (int p = ty; p < 1024; p += 16) s += pcs1[(long)p * 1024 + col];
        red[ty][tx] = s;
        __syncthreads();
        if (ty == 0) {
            float t = 0.f;
            #pragma unroll
            for (int q = 0; q < 16; ++q) t += red[q][tx];
            rcs1[col] = 1.f / t;
        }
    } else {
        const int col = (blockIdx.x - 16) * 64 + tx;
        float s = 0.f;
        for (int p = ty; p < 32; p += 16) s += pcs2[(long)p * 1024 + col];
        red[ty][tx] = s;
        __syncthreads();
        if (ty == 0) {
            float t = 0.f;
            #pragma unroll
            for (int q = 0; q < 16; ++q) t += red[q][tx];
            rcs2[col] = 1.f / t;
        }
    }
}

// ---- v-GEMM (BK=32 dbuf, counted vmcnt, 4 blocks/CU) + res + out-accum ----
__global__ __launch_bounds__(256) void gemm_v_res_out(
    const __hip_bfloat16* __restrict__ A, const __hip_bfloat16* __restrict__ Bt,
    const __hip_bfloat16* __restrict__ e1, const __hip_bfloat16* __restrict__ e2,
    const float* __restrict__ rcs1, const float* __restrict__ rcs2,
    const float* __restrict__ invde, const float* __restrict__ feats,
    const float* __restrict__ lpe, const __hip_bfloat16* __restrict__ fc2T,
    float* __restrict__ out)
{
    __shared__ __align__(16) char smem[34816];   // 2x(A 8K + B 8K) dbuf / st[128][136]
    unsigned short* st = (unsigned short*)smem;

    const int tid = threadIdx.x;
    const int wid = tid >> 6;
    const int lane = tid & 63;
    const int swz = xcd_swz(blockIdx.y * gridDim.x + blockIdx.x, gridDim.x * gridDim.y);
    const int bm = (swz >> 3) << 7, bn = (swz & 7) << 7;
    const int wm = (wid >> 1) << 6, wn = (wid & 1) << 6;

    f32x4 acc[4][4] = {};
    const int l15 = lane & 15;
    const int kg = lane >> 4;
    const int arow = wm + l15;
    const int brow = wn + l15;

    // staging: 2 chunks per thread per matrix; chunk idx = i*256+tid,
    // r = idx>>2, slot = idx&3, global chunk = slot ^ ((r>>1)&3)
#define VR_STAGE(b, k0)                                                         \
    { char* base = smem + (b) * 16384;                                          \
      _Pragma("unroll") for (int i = 0; i < 2; ++i) {                           \
        const int idx = i * 256 + tid;                                          \
        const int r = idx >> 2;                                                 \
        const int c4s = (idx & 3) ^ ((r >> 1) & 3);                             \
        GLOAD_LDS16(A + (long)(bm + r) * 1024 + (k0) + c4s * 8,                 \
                    base + (i * 256 + wid * 64) * 16);                          \
        GLOAD_LDS16(Bt + (long)(bn + r) * 1024 + (k0) + c4s * 8,                \
                    base + 8192 + (i * 256 + wid * 64) * 16); } }

    VR_STAGE(0, 0);
    #pragma unroll 2
    for (int kt = 0; kt < 32; ++kt) {
        if (kt < 31) {
            VR_STAGE((kt + 1) & 1, (kt + 1) * 32);
            asm volatile("s_waitcnt vmcnt(4)" ::: "memory");
        } else {
            asm volatile("s_waitcnt vmcnt(0)" ::: "memory");
        }
        __builtin_amdgcn_s_barrier();
        __builtin_amdgcn_sched_barrier(0);
        const char* AsB = smem + (kt & 1) * 16384;
        const char* BsB = AsB + 8192;
        short8 af[4], bf_[4];
        #pragma unroll
        for (int m = 0; m < 4; ++m) {
            const int R = arow + m * 16;
            af[m] = *(const short8*)(AsB + R * 64 + ((kg ^ ((R >> 1) & 3)) << 4));
        }
        #pragma unroll
        for (int n = 0; n < 4; ++n) {
            const int R = brow + n * 16;
            bf_[n] = *(const short8*)(BsB + R * 64 + ((kg ^ ((R >> 1) & 3)) << 4));
        }
        __builtin_amdgcn_s_setprio(1);
        #pragma unroll
        for (int m = 0; m < 4; ++m)
            #pragma unroll
            for (int n = 0; n < 4; ++n)
                acc[m][n] = __builtin_amdgcn_mfma_f32_16x16x32_bf16(
                    af[m], bf_[n], acc[m][n], 0, 0, 0);
        __builtin_amdgcn_s_setprio(0);
        __builtin_amdgcn_s_barrier();
    }
#undef VR_STAGE

    // v tile -> st (bf16)
    const int rq = kg << 2;
    #pragma unroll
    for (int m = 0; m < 4; ++m)
        #pragma unroll
        for (int n = 0; n < 4; ++n)
            #pragma unroll
            for (int j = 0; j < 4; ++j)
                st[(wm + m * 16 + rq + j) * 136 + wn + n * 16 + l15] =
                    f2bf_bits(acc[m][n][j]);
    __syncthreads();

    // res = (e1*rcs1 + e2*rcs2) * (v + pe) -> st in place (vectorized)
    const float lp = lpe[0];
    #pragma unroll
    for (int p = 0; p < 4; ++p) {
        const int r = p * 32 + (tid >> 3);
        const int cc = (tid & 7) << 4;
        const int grow = bm + r;
        const float angs = 100.f * feats[(long)grow * 64];
        const long goff = (long)grow * 1024 + bn + cc;
        const long goff2 = (long)(grow & 2047) * 1024 + bn + cc;
        short8 ev1[2], ev2[2], sv[2];
        ev1[0] = *(const short8*)((const unsigned short*)e1 + goff);
        ev1[1] = *(const short8*)((const unsigned short*)e1 + goff + 8);
        ev2[0] = *(const short8*)((const unsigned short*)e2 + goff2);
        ev2[1] = *(const short8*)((const unsigned short*)e2 + goff2 + 8);
        sv[0] = *(const short8*)&st[r * 136 + cc];
        sv[1] = *(const short8*)&st[r * 136 + cc + 8];
        unsigned short ov[16];
        #pragma unroll
        for (int q = 0; q < 16; ++q) {
            const int h = bn + cc + q;
            const float ang = angs * invde[h & 511];
            const float tr = (h < 512) ? __sinf(ang) : __cosf(ang);
            const float a = bf_bits2f((unsigned short)ev1[q >> 3][q & 7]) * rcs1[h] +
                            bf_bits2f((unsigned short)ev2[q >> 3][q & 7]) * rcs2[h];
            const float vv = bf_bits2f((unsigned short)sv[q >> 3][q & 7]);
            ov[q] = f2bf_bits(a * (vv + (tr + lp) * lp));
        }
        *(short8*)&st[r * 136 + cc] = *(short8*)&ov[0];
        *(short8*)&st[r * 136 + cc + 8] = *(short8*)&ov[8];
    }
    __syncthreads();

    // out[bm:+128, :] += res_tile @ fc2_w[bn:+128, :]
    {
        const int wmO = wid << 5;
        f32x4 aco[2][4] = {};
        #pragma unroll
        for (int ks = 0; ks < 4; ++ks) {
            short8 afo[2], bfo[4];
            #pragma unroll
            for (int m = 0; m < 2; ++m)
                afo[m] = *(const short8*)&st[(wmO + m * 16 + l15) * 136 + ks * 32 + kg * 8];
            #pragma unroll
            for (int n = 0; n < 4; ++n)
                bfo[n] = *(const short8*)((const unsigned short*)fc2T +
                                          (long)(n * 16 + l15) * 1024 + bn + ks * 32 + kg * 8);
            #pragma unroll
            for (int m = 0; m < 2; ++m)
                #pragma unroll
                for (int n = 0; n < 4; ++n)
                    aco[m][n] = __builtin_amdgcn_mfma_f32_16x16x32_bf16(
                        afo[m], bfo[n], aco[m][n], 0, 0, 0);
        }
        #pragma unroll
        for (int m = 0; m < 2; ++m)
            #pragma unroll
            for (int n = 0; n < 4; ++n)
                #pragma unroll
                for (int j = 0; j < 4; ++j) {
                    const int row = bm + wmO + m * 16 + rq + j;
                    atomicAdd(&out[(long)row * 64 + n * 16 + l15], aco[m][n][j]);
                }
    }
}

extern "C" void kernel_launch(void* const* d_in, const int* in_sizes, int n_in,
                              void* d_out, int out_size, void* d_ws, size_t ws_size,
                              hipStream_t stream) {
    const float* features = (const float*)d_in[0];
    const float* fc1_w = (const float*)d_in[1];
    const float* fc1_b = (const float*)d_in[2];
    const float* fc2_w = (const float*)d_in[3];
    const float* fc2_b = (const float*)d_in[4];
    const float* g1_w = (const float*)d_in[5];
    const float* g1_b = (const float*)d_in[6];
    const float* g2_w = (const float*)d_in[7];
    const float* g2_b = (const float*)d_in[8];
    const float* gg1_w = (const float*)d_in[9];
    const float* gg1_b = (const float*)d_in[10];
    const float* gg2_w = (const float*)d_in[11];
    const float* gg2_b = (const float*)d_in[12];
    const float* wq = (const float*)d_in[13];
    const float* wk = (const float*)d_in[14];
    const float* wv = (const float*)d_in[15];
    const float* wq2 = (const float*)d_in[16];
    const float* wk2 = (const float*)d_in[17];
    const float* lpe = (const float*)d_in[18];
    float* out = (float*)d_out;

    char* ws = (char*)d_ws;
    const size_t MB = 1024ull * 1024ull;
    __hip_bfloat16* xb   = (__hip_bfloat16*)ws;                 // 32 MB
    __hip_bfloat16* e1   = (__hip_bfloat16*)(ws + 32 * MB);     // 32 MB
    __hip_bfloat16* d2b  = (__hip_bfloat16*)(ws + 64 * MB);     // 4 MB
    __hip_bfloat16* t2b  = (__hip_bfloat16*)(ws + 68 * MB);     // 4 MB
    __hip_bfloat16* e2b  = (__hip_bfloat16*)(ws + 72 * MB);     // 4 MB
    float*          pcs1 = (float*)(ws + 76 * MB);              // 4 MB
    float*          pcs2 = (float*)(ws + 80 * MB);              // 128 KB
    char* W = ws + 81 * MB;
    __hip_bfloat16* wdT   = (__hip_bfloat16*)W;                 // 2 MB
    __hip_bfloat16* wvT   = (__hip_bfloat16*)(W + 2 * MB);      // 2 MB
    __hip_bfloat16* g1T   = (__hip_bfloat16*)(W + 4 * MB);      // 2 MB
    __hip_bfloat16* g2T   = (__hip_bfloat16*)(W + 6 * MB);      // 2 MB
    __hip_bfloat16* fc2T  = (__hip_bfloat16*)(W + 8 * MB);      // 128 KB
    __hip_bfloat16* wd2T  = (__hip_bfloat16*)(W + 8 * MB + 256 * 1024);
    __hip_bfloat16* gg1T  = (__hip_bfloat16*)(W + 8 * MB + 320 * 1024);
    __hip_bfloat16* gg2T  = (__hip_bfloat16*)(W + 8 * MB + 384 * 1024);
    float* rcs1  = (float*)(W + 9 * MB);                        // 4 KB
    float* rcs2  = rcs1 + 1024;
    float* invde = rcs2 + 1024;                                 // 512

    // 1. prep (transposes, out-init, invde) + x-GEMM from fp32
    prep_x_k<<<5489, 256, 0, stream>>>(
        features, fc1_w, fc1_b, fc2_w, fc2_b, g1_w, g2_w, wq, wk, wv, wq2, wk2,
        gg1_w, gg2_w, fc2T, wdT, wvT, g1T, g2T, wd2T, gg1T, gg2T, xb, invde, out);

    // 2. chain (1024 tiles) + tail GEMM 1 (512 blocks, 64x64 tiles)
    mid_k<<<1536, 256, 0, stream>>>(xb, wdT, d2b, wd2T, gg1T, gg2T,
                                    gg1_b, gg2_b, e1, pcs1);

    // 3-4. tail GEMMs 2,3 (64x64 tiles, 512-block grids, dbuf)
    gemm6464_k<1, false><<<dim3(16, 32), 256, 0, stream>>>(d2b, g1T, g1_b, t2b, 0.f, nullptr);
    gemm6464_k<2, true><<<dim3(16, 32), 256, 0, stream>>>(t2b, g2T, g2_b, e2b, 0.03125f, pcs2);

    // 5. softmax denominators -> reciprocals
    reduce_k<<<32, dim3(64, 16), 0, stream>>>(pcs1, pcs2, rcs1, rcs2);

    // 6. v-GEMM + res epilogue + out-accum
    gemm_v_res_out<<<dim3(8, 128), 256, 0, stream>>>(
        xb, wvT, e1, e2b, rcs1, rcs2, invde, features, lpe, fc2T, out);
}

// Round 9
// 289.933 us; speedup vs baseline: 1.0370x; 1.0370x over previous
//
#include <hip/hip_runtime.h>
#include <hip/hip_bf16.h>
#include <math.h>
#include <type_traits>

// Round 9: measurement + revert round.
//  - Every phase its own named kernel (top-5 was 100% vres replays; need the
//    real distribution of the ~210us non-vres time).
//  - vres back to BK=64/vmcnt(8) (round-7 config: 82us vs round-8 BK=32 90us —
//    barrier count dominates; occupancy is VGPR-capped (112+64 AGPR) anyway).
//  - Transposes: 128x32 per block (4 sub-tiles), 4x fewer blocks.
//  - t1 unmerged from chain: no more 64KB-LDS penalty on its blocks.

typedef __attribute__((ext_vector_type(8))) short short8;
typedef __attribute__((ext_vector_type(4))) float f32x4;
typedef __attribute__((ext_vector_type(4))) float float4v;

#define GLOAD_LDS16(gptr, lptr)                                                 \
    __builtin_amdgcn_global_load_lds(                                           \
        (const __attribute__((address_space(1))) void*)(gptr),                  \
        (__attribute__((address_space(3))) void*)(lptr), 16, 0, 0)

static __device__ __forceinline__ unsigned short f2bf_bits(float v) {
    __hip_bfloat16 h = __float2bfloat16(v);
    return __builtin_bit_cast(unsigned short, h);
}
static __device__ __forceinline__ float bf_bits2f(unsigned short u) {
    return __bfloat162float(__builtin_bit_cast(__hip_bfloat16, u));
}
static __device__ __forceinline__ int swz16(int r, int c16) {
    return (r << 4) + (c16 ^ (r & 7));
}
static __device__ __forceinline__ int swz_elem(int r, int c) {
    return (r << 7) + ((((c << 1) ^ ((r & 7) << 4))) >> 1);
}
static __device__ __forceinline__ int xcd_swz(int bid, int nwg) {
    return (bid & 7) * (nwg >> 3) + (bid >> 3);
}

// ---------------- prep: transposes (128x32/block) + out-init + invde --------
static __device__ void conv_t_dev(const float* __restrict__ A, const float* __restrict__ Bsub,
                                  __hip_bfloat16* __restrict__ Ot, int K, int N,
                                  int bx, int by, int tid, float* t /* [32][33] */)
{
    const int n0 = bx * 32, k0 = by * 128;
    const int tx = tid & 31, ty = tid >> 5;
    const int ksub = (K - k0 < 128) ? (K - k0) / 32 : 4;
    for (int s = 0; s < ksub; ++s) {
        const int kk = k0 + s * 32;
        #pragma unroll
        for (int j = 0; j < 4; ++j) {
            int k = kk + ty + j * 8;
            float v = A[(long)k * N + n0 + tx];
            if (Bsub) v -= Bsub[(long)k * N + n0 + tx];
            t[(ty + j * 8) * 33 + tx] = v;
        }
        __syncthreads();
        #pragma unroll
        for (int j = 0; j < 4; ++j) {
            int n = n0 + ty + j * 8;
            Ot[(long)n * K + kk + tx] = __float2bfloat16(t[tx * 33 + ty + j * 8]);
        }
        __syncthreads();
    }
}

__global__ __launch_bounds__(256) void prep_k(
    const float* __restrict__ features, const float* __restrict__ fc2_w,
    const float* __restrict__ fc2_b, const float* __restrict__ g1_w,
    const float* __restrict__ g2_w, const float* __restrict__ wq,
    const float* __restrict__ wk, const float* __restrict__ wv,
    const float* __restrict__ wq2, const float* __restrict__ wk2,
    const float* __restrict__ gg1_w, const float* __restrict__ gg2_w,
    __hip_bfloat16* __restrict__ fc2T, __hip_bfloat16* __restrict__ wdT,
    __hip_bfloat16* __restrict__ wvT, __hip_bfloat16* __restrict__ g1T,
    __hip_bfloat16* __restrict__ g2T, __hip_bfloat16* __restrict__ wd2T,
    __hip_bfloat16* __restrict__ gg1T, __hip_bfloat16* __restrict__ gg2T,
    float* __restrict__ invde, float* __restrict__ out)
{
    __shared__ float t[32 * 33];
    const int bid = blockIdx.x;
    const int tid = threadIdx.x;

    if (bid == 0) {                       // invde LUT (512)
        #pragma unroll
        for (int i = 0; i < 2; ++i) {
            int idx = tid + i * 256;
            invde[idx] = exp2f(-9.96578428466209f * (float)idx * (1.f / 512.f));
        }
    } else if (bid < 257) {               // out = features + fc2_b  (1M fp32)
        const float4v* f4 = (const float4v*)features;
        float4v* o4 = (float4v*)out;
        const float4v* b4 = (const float4v*)fc2_b;
        long base = (long)(bid - 1) * 1024;
        #pragma unroll
        for (int i = 0; i < 4; ++i) {
            long idx = base + tid + i * 256;
            o4[idx] = f4[idx] + b4[idx & 15];
        }
    } else if (bid < 513) {               // wdT = (wq - wk)^T : 256 blocks
        int tt = bid - 257;  conv_t_dev(wq, wk, wdT, 1024, 1024, tt & 31, tt >> 5, tid, t);
    } else if (bid < 769) {               // wvT
        int tt = bid - 513;  conv_t_dev(wv, nullptr, wvT, 1024, 1024, tt & 31, tt >> 5, tid, t);
    } else if (bid < 1025) {              // g1T
        int tt = bid - 769;  conv_t_dev(g1_w, nullptr, g1T, 1024, 1024, tt & 31, tt >> 5, tid, t);
    } else if (bid < 1281) {              // g2T
        int tt = bid - 1025; conv_t_dev(g2_w, nullptr, g2T, 1024, 1024, tt & 31, tt >> 5, tid, t);
    } else if (bid < 1297) {              // fc2T (K=1024, N=64): 16 blocks
        int tt = bid - 1281; conv_t_dev(fc2_w, nullptr, fc2T, 1024, 64, tt & 1, tt >> 1, tid, t);
    } else if (bid < 1301) {              // wd2T (K=128,N=128): 4 blocks
        int tt = bid - 1297; conv_t_dev(wq2, wk2, wd2T, 128, 128, tt & 3, 0, tid, t);
    } else if (bid < 1305) {              // gg1T
        int tt = bid - 1301; conv_t_dev(gg1_w, nullptr, gg1T, 128, 128, tt & 3, 0, tid, t);
    } else {                              // gg2T
        int tt = bid - 1305; conv_t_dev(gg2_w, nullptr, gg2T, 128, 128, tt & 3, 0, tid, t);
    }
}

// ---------------- x-GEMM from fp32 inputs ----------------
__global__ __launch_bounds__(256) void xgemm_k(
    const float* __restrict__ features, const float* __restrict__ fc1_w,
    const float* __restrict__ fc1_b, __hip_bfloat16* __restrict__ xb)
{
    __shared__ __align__(16) char smem[32768];
    unsigned short* As = (unsigned short*)smem;            // [128][64] swizzled
    unsigned short* Bs = (unsigned short*)(smem + 16384);  // [128 n][64 k] swizzled
    const int tile = blockIdx.x;
    const int tid = threadIdx.x;
    const int bm = (tile >> 3) << 7, bn = (tile & 7) << 7;
    const int wid = tid >> 6, lane = tid & 63;
    const int wm = (wid >> 1) << 6, wn = (wid & 1) << 6;
    const int l15 = lane & 15, kg = lane >> 4;

    #pragma unroll
    for (int i = 0; i < 8; ++i) {
        int idx = i * 256 + tid;
        int r = idx >> 4, c4 = idx & 15;
        float4v f = *(const float4v*)(features + (long)(bm + r) * 64 + c4 * 4);
        unsigned int p0 = f2bf_bits(f[0]) | ((unsigned int)f2bf_bits(f[1]) << 16);
        unsigned int p1 = f2bf_bits(f[2]) | ((unsigned int)f2bf_bits(f[3]) << 16);
        int dst = r * 64 + (((c4 >> 1) ^ (r & 7)) << 3) + (c4 & 1) * 4;
        unsigned int* p = (unsigned int*)&As[dst];
        p[0] = p0; p[1] = p1;
    }
    #pragma unroll
    for (int i = 0; i < 8; ++i) {
        int idx = i * 256 + tid;
        int k = idx >> 5, c4b = idx & 31;
        float4v g = *(const float4v*)(fc1_w + (long)k * 1024 + bn + c4b * 4);
        #pragma unroll
        for (int q = 0; q < 4; ++q) {
            int n = c4b * 4 + q;
            Bs[n * 64 + (((k >> 3) ^ (n & 7)) << 3) + (k & 7)] = f2bf_bits(g[q]);
        }
    }
    __syncthreads();

    f32x4 acc[4][4] = {};
    #pragma unroll
    for (int ks2 = 0; ks2 < 2; ++ks2) {
        const int kslot = ks2 * 4 + kg;
        short8 af[4], bf_[4];
        #pragma unroll
        for (int m = 0; m < 4; ++m) {
            int r = wm + m * 16 + l15;
            af[m] = *(const short8*)&As[r * 64 + ((kslot ^ (r & 7)) << 3)];
        }
        #pragma unroll
        for (int n = 0; n < 4; ++n) {
            int r = wn + n * 16 + l15;
            bf_[n] = *(const short8*)&Bs[r * 64 + ((kslot ^ (r & 7)) << 3)];
        }
        #pragma unroll
        for (int m = 0; m < 4; ++m)
            #pragma unroll
            for (int n = 0; n < 4; ++n)
                acc[m][n] = __builtin_amdgcn_mfma_f32_16x16x32_bf16(
                    af[m], bf_[n], acc[m][n], 0, 0, 0);
    }
    const int rq = kg << 2;
    #pragma unroll
    for (int n = 0; n < 4; ++n) {
        const int col = bn + wn + n * 16 + l15;
        const float bv = fc1_b[col];
        #pragma unroll
        for (int m = 0; m < 4; ++m)
            #pragma unroll
            for (int j = 0; j < 4; ++j)
                xb[(long)(bm + wm + m * 16 + rq + j) * 1024 + col] =
                    __float2bfloat16(acc[m][n][j] + bv);
    }
}

// ------- 64x64 GEMM, BK=32, counted-vmcnt double-buffer -------
template <int OP, bool CS>
static __device__ void gemm6464_dev(
    const __hip_bfloat16* __restrict__ A, const __hip_bfloat16* __restrict__ Bt,
    const float* __restrict__ bias, __hip_bfloat16* __restrict__ Co,
    float scale, float* __restrict__ pcs, int swz, int tid, char* smem)
{
    const int wid = tid >> 6, lane = tid & 63;
    const int bm = (swz >> 4) << 6, bn = (swz & 15) << 6;
    const int wm = (wid >> 1) << 5, wn = (wid & 1) << 5;
    f32x4 acc[2][2] = {};
    const int l15 = lane & 15, kg = lane >> 4;
    const int rS = tid >> 2;
    const int c4s = (tid & 3) ^ ((rS >> 1) & 3);

#define G66_STAGE(b, k0)                                                        \
    { char* base = smem + (b) * 8192;                                           \
      GLOAD_LDS16(A + (long)(bm + rS) * 1024 + (k0) + c4s * 8,                  \
                  base + (wid << 6) * 16);                                      \
      GLOAD_LDS16(Bt + (long)(bn + rS) * 1024 + (k0) + c4s * 8,                 \
                  base + 4096 + (wid << 6) * 16); }

    G66_STAGE(0, 0);
    #pragma unroll 2
    for (int kt = 0; kt < 32; ++kt) {
        if (kt < 31) {
            G66_STAGE((kt + 1) & 1, (kt + 1) * 32);
            asm volatile("s_waitcnt vmcnt(2)" ::: "memory");
        } else {
            asm volatile("s_waitcnt vmcnt(0)" ::: "memory");
        }
        __builtin_amdgcn_s_barrier();
        __builtin_amdgcn_sched_barrier(0);
        const char* AsB = smem + (kt & 1) * 8192;
        const char* BsB = AsB + 4096;
        short8 af[2], bf_[2];
        #pragma unroll
        for (int m = 0; m < 2; ++m) {
            const int R = wm + m * 16 + l15;
            af[m] = *(const short8*)(AsB + R * 64 + ((kg ^ ((R >> 1) & 3)) << 4));
        }
        #pragma unroll
        for (int n = 0; n < 2; ++n) {
            const int R = wn + n * 16 + l15;
            bf_[n] = *(const short8*)(BsB + R * 64 + ((kg ^ ((R >> 1) & 3)) << 4));
        }
        __builtin_amdgcn_s_setprio(1);
        #pragma unroll
        for (int m = 0; m < 2; ++m)
            #pragma unroll
            for (int n = 0; n < 2; ++n)
                acc[m][n] = __builtin_amdgcn_mfma_f32_16x16x32_bf16(
                    af[m], bf_[n], acc[m][n], 0, 0, 0);
        __builtin_amdgcn_s_setprio(0);
        __builtin_amdgcn_s_barrier();
    }
#undef G66_STAGE

    const int rq = kg << 2;
    float csum[2];
    #pragma unroll
    for (int n = 0; n < 2; ++n) {
        const int col = bn + wn + n * 16 + l15;
        const float bv = bias ? bias[col] : 0.f;
        csum[n] = 0.f;
        #pragma unroll
        for (int m = 0; m < 2; ++m) {
            #pragma unroll
            for (int j = 0; j < 4; ++j) {
                const int row = bm + wm + m * 16 + rq + j;
                float cv = acc[m][n][j] + bv;
                if (OP == 1) cv = fmaxf(cv, 0.f);
                if (OP == 2) cv = __expf(cv * scale);
                if (CS) csum[n] += cv;
                Co[(long)row * 1024 + col] = __float2bfloat16(cv);
            }
        }
    }
    if (CS) {
        __syncthreads();
        float* ps = (float*)smem;
        const int slot = ((wid >> 1) << 2) | kg;
        #pragma unroll
        for (int n = 0; n < 2; ++n)
            ps[(wn + n * 16 + l15) * 8 + slot] = csum[n];
        __syncthreads();
        if (tid < 64) {
            float s = 0.f;
            #pragma unroll
            for (int q = 0; q < 8; ++q) s += ps[tid * 8 + q];
            pcs[(long)(swz >> 4) * 1024 + bn + tid] = s;
        }
    }
}

__global__ __launch_bounds__(256) void t1_k(
    const __hip_bfloat16* __restrict__ A, const __hip_bfloat16* __restrict__ Bt,
    __hip_bfloat16* __restrict__ Co)
{
    __shared__ __align__(16) char smem[16384];
    const int swz = xcd_swz(blockIdx.y * gridDim.x + blockIdx.x, gridDim.x * gridDim.y);
    gemm6464_dev<0, false>(A, Bt, nullptr, Co, 0.f, nullptr, swz, threadIdx.x, smem);
}
__global__ __launch_bounds__(256) void t2_k(
    const __hip_bfloat16* __restrict__ A, const __hip_bfloat16* __restrict__ Bt,
    const float* __restrict__ bias, __hip_bfloat16* __restrict__ Co)
{
    __shared__ __align__(16) char smem[16384];
    const int swz = xcd_swz(blockIdx.y * gridDim.x + blockIdx.x, gridDim.x * gridDim.y);
    gemm6464_dev<1, false>(A, Bt, bias, Co, 0.f, nullptr, swz, threadIdx.x, smem);
}
__global__ __launch_bounds__(256) void t3_k(
    const __hip_bfloat16* __restrict__ A, const __hip_bfloat16* __restrict__ Bt,
    const float* __restrict__ bias, __hip_bfloat16* __restrict__ Co,
    float* __restrict__ pcs)
{
    __shared__ __align__(16) char smem[16384];
    const int swz = xcd_swz(blockIdx.y * gridDim.x + blockIdx.x, gridDim.x * gridDim.y);
    gemm6464_dev<2, true>(A, Bt, bias, Co, 0.03125f, pcs, swz, threadIdx.x, smem);
}

// ---------------- fused group-MLP chain ----------------
__global__ __launch_bounds__(256) void chain_k(
    const __hip_bfloat16* __restrict__ xb,
    const __hip_bfloat16* __restrict__ w1T,
    const __hip_bfloat16* __restrict__ w2T,
    const __hip_bfloat16* __restrict__ w3T,
    const float* __restrict__ b2, const float* __restrict__ b3,
    __hip_bfloat16* __restrict__ e1, float* __restrict__ pcs1)
{
    __shared__ __align__(16) char smem[65536];
    unsigned short* act = (unsigned short*)smem;
    unsigned short* Wb  = (unsigned short*)(smem + 32768);
    const int tid = threadIdx.x;
    const int wid = tid >> 6, lane = tid & 63;
    const int wm = (wid >> 1) << 6, wn = (wid & 1) << 6;
    const int tileIdx = blockIdx.x;
    const long tile = (long)tileIdx * (128 * 128);

    #pragma unroll
    for (int i = 0; i < 8; ++i) {
        int L = i * 256 + wid * 64 + lane;
        int r = L >> 4, c16o = (L & 15) ^ (r & 7);
        GLOAD_LDS16(xb + tile + r * 128 + c16o * 8,
                    (char*)act + (i * 256 + wid * 64) * 16);
        GLOAD_LDS16(w1T + r * 128 + c16o * 8,
                    (char*)Wb + (i * 256 + wid * 64) * 16);
    }
    __syncthreads();

    f32x4 acc[4][4];
    const int rq = (lane >> 4) << 2;

#define CHAIN_ZERO()                                                            \
    _Pragma("unroll") for (int m = 0; m < 4; ++m)                               \
        _Pragma("unroll") for (int n = 0; n < 4; ++n)                           \
            acc[m][n] = (f32x4){0.f, 0.f, 0.f, 0.f};

#define CHAIN_MM()                                                              \
    _Pragma("unroll") for (int ks = 0; ks < 4; ++ks) {                          \
        short8 af[4], bfv[4];                                                   \
        const int kc = ks * 4 + (lane >> 4);                                    \
        _Pragma("unroll") for (int m = 0; m < 4; ++m) {                         \
            int r = wm + m * 16 + (lane & 15);                                  \
            af[m] = *(const short8*)((const char*)act + swz16(r, kc) * 16);     \
        }                                                                       \
        _Pragma("unroll") for (int n = 0; n < 4; ++n) {                         \
            int r = wn + n * 16 + (lane & 15);                                  \
            bfv[n] = *(const short8*)((const char*)Wb + swz16(r, kc) * 16);     \
        }                                                                       \
        _Pragma("unroll") for (int m = 0; m < 4; ++m)                           \
            _Pragma("unroll") for (int n = 0; n < 4; ++n)                       \
                acc[m][n] = __builtin_amdgcn_mfma_f32_16x16x32_bf16(            \
                    af[m], bfv[n], acc[m][n], 0, 0, 0);                         \
    }

#define STAGE_W(wptr)                                                           \
    _Pragma("unroll") for (int i = 0; i < 8; ++i) {                             \
        int L = i * 256 + wid * 64 + lane;                                      \
        int r = L >> 4, c16o = (L & 15) ^ (r & 7);                              \
        GLOAD_LDS16((wptr) + r * 128 + c16o * 8,                                \
                    (char*)Wb + (i * 256 + wid * 64) * 16);                     \
    }

    CHAIN_ZERO(); CHAIN_MM();
    __syncthreads();
    STAGE_W(w2T);
    #pragma unroll
    for (int m = 0; m < 4; ++m)
        #pragma unroll
        for (int n = 0; n < 4; ++n)
            #pragma unroll
            for (int j = 0; j < 4; ++j) {
                int row = wm + m * 16 + rq + j, col = wn + n * 16 + (lane & 15);
                act[swz_elem(row, col)] = f2bf_bits(acc[m][n][j]);
            }
    __syncthreads();

    CHAIN_ZERO(); CHAIN_MM();
    __syncthreads();
    STAGE_W(w3T);
    {
        float bv[4];
        #pragma unroll
        for (int n = 0; n < 4; ++n) bv[n] = b2[wn + n * 16 + (lane & 15)];
        #pragma unroll
        for (int m = 0; m < 4; ++m)
            #pragma unroll
            for (int n = 0; n < 4; ++n)
                #pragma unroll
                for (int j = 0; j < 4; ++j) {
                    int row = wm + m * 16 + rq + j, col = wn + n * 16 + (lane & 15);
                    act[swz_elem(row, col)] = f2bf_bits(fmaxf(acc[m][n][j] + bv[n], 0.f));
                }
    }
    __syncthreads();

    CHAIN_ZERO(); CHAIN_MM();
    __syncthreads();
    {
        float bv[4];
        #pragma unroll
        for (int n = 0; n < 4; ++n) bv[n] = b3[wn + n * 16 + (lane & 15)];
        #pragma unroll
        for (int m = 0; m < 4; ++m)
            #pragma unroll
            for (int n = 0; n < 4; ++n)
                #pragma unroll
                for (int j = 0; j < 4; ++j) {
                    int row = wm + m * 16 + rq + j, col = wn + n * 16 + (lane & 15);
                    float ev = __expf((acc[m][n][j] + bv[n]) * 0.08838834764831845f);
                    act[swz_elem(row, col)] = f2bf_bits(ev);
                }
    }
    __syncthreads();

    #pragma unroll
    for (int i = 0; i < 8; ++i) {
        int idx = i * 256 + tid;
        int r = idx >> 4, c16o = idx & 15;
        short8 vd = *(const short8*)((const char*)act + swz16(r, c16o) * 16);
        *(short8*)((__hip_bfloat16*)e1 + tile + r * 128 + c16o * 8) = vd;
    }
    #pragma unroll
    for (int i = 0; i < 4; ++i) {
        int p = i * 256 + tid;
        int g = p >> 7, c = p & 127;
        float s = 0.f;
        #pragma unroll
        for (int t16 = 0; t16 < 16; ++t16) {
            int r = t16 * 8 + g;
            s += bf_bits2f(act[swz_elem(r, c)]);
        }
        pcs1[(long)tileIdx * 1024 + p] = s;
    }
#undef CHAIN_ZERO
#undef CHAIN_MM
#undef STAGE_W
}

// reduce: blocks 0-15 -> rcs1, 16-31 -> rcs2
__global__ __launch_bounds__(1024) void reduce_k(
    const float* __restrict__ pcs1, const float* __restrict__ pcs2,
    float* __restrict__ rcs1, float* __restrict__ rcs2)
{
    __shared__ float red[16][64];
    const int tx = threadIdx.x, ty = threadIdx.y;
    if (blockIdx.x < 16) {
        const int col = blockIdx.x * 64 + tx;
        float s = 0.f;
        for (int p = ty; p < 1024; p += 16) s += pcs1[(long)p * 1024 + col];
        red[ty][tx] = s;
        __syncthreads();
        if (ty == 0) {
            float t = 0.f;
            #pragma unroll
            for (int q = 0; q < 16; ++q) t += red[q][tx];
            rcs1[col] = 1.f / t;
        }
    } else {
        const int col = (blockIdx.x - 16) * 64 + tx;
        float s = 0.f;
        for (int p = ty; p < 32; p += 16) s += pcs2[(long)p * 1024 + col];
        red[ty][tx] = s;
        __syncthreads();
        if (ty == 0) {
            float t = 0.f;
            #pragma unroll
            for (int q = 0; q < 16; ++q) t += red[q][tx];
            rcs2[col] = 1.f / t;
        }
    }
}

// ---- v-GEMM (BK=64 dbuf, vmcnt(8)) + res epilogue + out-accum ----
__global__ __launch_bounds__(256) void vres_k(
    const __hip_bfloat16* __restrict__ A, const __hip_bfloat16* __restrict__ Bt,
    const __hip_bfloat16* __restrict__ e1, const __hip_bfloat16* __restrict__ e2,
    const float* __restrict__ rcs1, const float* __restrict__ rcs2,
    const float* __restrict__ invde, const float* __restrict__ feats,
    const float* __restrict__ lpe, const __hip_bfloat16* __restrict__ fc2T,
    float* __restrict__ out)
{
    __shared__ __align__(16) char smem[65536];            // 2x(As 16K + Bs 16K)
    unsigned short* st = (unsigned short*)smem;           // [128][136] epilogue union

    const int tid = threadIdx.x;
    const int wid = tid >> 6;
    const int lane = tid & 63;
    const int swz = xcd_swz(blockIdx.y * gridDim.x + blockIdx.x, gridDim.x * gridDim.y);
    const int bm = (swz >> 3) << 7, bn = (swz & 7) << 7;
    const int wm = (wid >> 1) << 6, wn = (wid & 1) << 6;

    f32x4 acc[4][4] = {};
    const int c8 = tid & 7;
    const int l15 = lane & 15;
    const int kg = lane >> 4;
    const int arow = wm + l15;
    const int brow = wn + l15;

#define VR_STAGE(b, k0)                                                         \
    { char* base = smem + (b) * 32768;                                          \
      _Pragma("unroll") for (int i = 0; i < 4; ++i) {                           \
        const int r = i * 32 + (tid >> 3);                                      \
        const int c8s = c8 ^ (r & 7);                                           \
        GLOAD_LDS16(A + (long)(bm + r) * 1024 + (k0) + c8s * 8,                 \
                    base + (i * 256 + wid * 64) * 16);                          \
        GLOAD_LDS16(Bt + (long)(bn + r) * 1024 + (k0) + c8s * 8,                \
                    base + 16384 + (i * 256 + wid * 64) * 16); } }

    VR_STAGE(0, 0);
    #pragma unroll 2
    for (int kt = 0; kt < 16; ++kt) {
        if (kt < 15) {
            VR_STAGE((kt + 1) & 1, (kt + 1) * 64);
            asm volatile("s_waitcnt vmcnt(8)" ::: "memory");
        } else {
            asm volatile("s_waitcnt vmcnt(0)" ::: "memory");
        }
        __builtin_amdgcn_s_barrier();
        __builtin_amdgcn_sched_barrier(0);
        const __hip_bfloat16* As = (const __hip_bfloat16*)(smem + (kt & 1) * 32768);
        const __hip_bfloat16* Bs = (const __hip_bfloat16*)(smem + (kt & 1) * 32768 + 16384);
        __builtin_amdgcn_s_setprio(1);
        #pragma unroll
        for (int ks2 = 0; ks2 < 2; ++ks2) {
            const int kslot = ks2 * 4 + kg;
            short8 af[4], bf_[4];
            #pragma unroll
            for (int m = 0; m < 4; ++m) {
                const int r = arow + m * 16;
                af[m] = *(const short8*)(As + (r * 8 + (kslot ^ (r & 7))) * 8);
            }
            #pragma unroll
            for (int n = 0; n < 4; ++n) {
                const int r = brow + n * 16;
                bf_[n] = *(const short8*)(Bs + (r * 8 + (kslot ^ (r & 7))) * 8);
            }
            #pragma unroll
            for (int m = 0; m < 4; ++m)
                #pragma unroll
                for (int n = 0; n < 4; ++n)
                    acc[m][n] = __builtin_amdgcn_mfma_f32_16x16x32_bf16(
                        af[m], bf_[n], acc[m][n], 0, 0, 0);
        }
        __builtin_amdgcn_s_setprio(0);
        __builtin_amdgcn_s_barrier();
    }
#undef VR_STAGE

    // v tile -> st (bf16)
    const int rq = kg << 2;
    #pragma unroll
    for (int m = 0; m < 4; ++m)
        #pragma unroll
        for (int n = 0; n < 4; ++n)
            #pragma unroll
            for (int j = 0; j < 4; ++j)
                st[(wm + m * 16 + rq + j) * 136 + wn + n * 16 + l15] =
                    f2bf_bits(acc[m][n][j]);
    __syncthreads();

    // res = (e1*rcs1 + e2*rcs2) * (v + pe) -> st in place (vectorized)
    const float lp = lpe[0];
    #pragma unroll
    for (int p = 0; p < 4; ++p) {
        const int r = p * 32 + (tid >> 3);
        const int cc = (tid & 7) << 4;
        const int grow = bm + r;
        const float angs = 100.f * feats[(long)grow * 64];
        const long goff = (long)grow * 1024 + bn + cc;
        const long goff2 = (long)(grow & 2047) * 1024 + bn + cc;
        short8 ev1[2], ev2[2], sv[2];
        ev1[0] = *(const short8*)((const unsigned short*)e1 + goff);
        ev1[1] = *(const short8*)((const unsigned short*)e1 + goff + 8);
        ev2[0] = *(const short8*)((const unsigned short*)e2 + goff2);
        ev2[1] = *(const short8*)((const unsigned short*)e2 + goff2 + 8);
        sv[0] = *(const short8*)&st[r * 136 + cc];
        sv[1] = *(const short8*)&st[r * 136 + cc + 8];
        unsigned short ov[16];
        #pragma unroll
        for (int q = 0; q < 16; ++q) {
            const int h = bn + cc + q;
            const float ang = angs * invde[h & 511];
            const float tr = (h < 512) ? __sinf(ang) : __cosf(ang);
            const float a = bf_bits2f((unsigned short)ev1[q >> 3][q & 7]) * rcs1[h] +
                            bf_bits2f((unsigned short)ev2[q >> 3][q & 7]) * rcs2[h];
            const float vv = bf_bits2f((unsigned short)sv[q >> 3][q & 7]);
            ov[q] = f2bf_bits(a * (vv + (tr + lp) * lp));
        }
        *(short8*)&st[r * 136 + cc] = *(short8*)&ov[0];
        *(short8*)&st[r * 136 + cc + 8] = *(short8*)&ov[8];
    }
    __syncthreads();

    // out[bm:+128, :] += res_tile @ fc2_w[bn:+128, :]
    {
        const int wmO = wid << 5;
        f32x4 aco[2][4] = {};
        #pragma unroll
        for (int ks = 0; ks < 4; ++ks) {
            short8 afo[2], bfo[4];
            #pragma unroll
            for (int m = 0; m < 2; ++m)
                afo[m] = *(const short8*)&st[(wmO + m * 16 + l15) * 136 + ks * 32 + kg * 8];
            #pragma unroll
            for (int n = 0; n < 4; ++n)
                bfo[n] = *(const short8*)((const unsigned short*)fc2T +
                                          (long)(n * 16 + l15) * 1024 + bn + ks * 32 + kg * 8);
            #pragma unroll
            for (int m = 0; m < 2; ++m)
                #pragma unroll
                for (int n = 0; n < 4; ++n)
                    aco[m][n] = __builtin_amdgcn_mfma_f32_16x16x32_bf16(
                        afo[m], bfo[n], aco[m][n], 0, 0, 0);
        }
        #pragma unroll
        for (int m = 0; m < 2; ++m)
            #pragma unroll
            for (int n = 0; n < 4; ++n)
                #pragma unroll
                for (int j = 0; j < 4; ++j) {
                    const int row = bm + wmO + m * 16 + rq + j;
                    atomicAdd(&out[(long)row * 64 + n * 16 + l15], aco[m][n][j]);
                }
    }
}

extern "C" void kernel_launch(void* const* d_in, const int* in_sizes, int n_in,
                              void* d_out, int out_size, void* d_ws, size_t ws_size,
                              hipStream_t stream) {
    const float* features = (const float*)d_in[0];
    const float* fc1_w = (const float*)d_in[1];
    const float* fc1_b = (const float*)d_in[2];
    const float* fc2_w = (const float*)d_in[3];
    const float* fc2_b = (const float*)d_in[4];
    const float* g1_w = (const float*)d_in[5];
    const float* g1_b = (const float*)d_in[6];
    const float* g2_w = (const float*)d_in[7];
    const float* g2_b = (const float*)d_in[8];
    const float* gg1_w = (const float*)d_in[9];
    const float* gg1_b = (const float*)d_in[10];
    const float* gg2_w = (const float*)d_in[11];
    const float* gg2_b = (const float*)d_in[12];
    const float* wq = (const float*)d_in[13];
    const float* wk = (const float*)d_in[14];
    const float* wv = (const float*)d_in[15];
    const float* wq2 = (const float*)d_in[16];
    const float* wk2 = (const float*)d_in[17];
    const float* lpe = (const float*)d_in[18];
    float* out = (float*)d_out;

    char* ws = (char*)d_ws;
    const size_t MB = 1024ull * 1024ull;
    __hip_bfloat16* xb   = (__hip_bfloat16*)ws;                 // 32 MB
    __hip_bfloat16* e1   = (__hip_bfloat16*)(ws + 32 * MB);     // 32 MB
    __hip_bfloat16* d2b  = (__hip_bfloat16*)(ws + 64 * MB);     // 4 MB
    __hip_bfloat16* t2b  = (__hip_bfloat16*)(ws + 68 * MB);     // 4 MB
    __hip_bfloat16* e2b  = (__hip_bfloat16*)(ws + 72 * MB);     // 4 MB
    float*          pcs1 = (float*)(ws + 76 * MB);              // 4 MB
    float*          pcs2 = (float*)(ws + 80 * MB);              // 128 KB
    char* W = ws + 81 * MB;
    __hip_bfloat16* wdT   = (__hip_bfloat16*)W;                 // 2 MB
    __hip_bfloat16* wvT   = (__hip_bfloat16*)(W + 2 * MB);      // 2 MB
    __hip_bfloat16* g1T   = (__hip_bfloat16*)(W + 4 * MB);      // 2 MB
    __hip_bfloat16* g2T   = (__hip_bfloat16*)(W + 6 * MB);      // 2 MB
    __hip_bfloat16* fc2T  = (__hip_bfloat16*)(W + 8 * MB);      // 128 KB
    __hip_bfloat16* wd2T  = (__hip_bfloat16*)(W + 8 * MB + 256 * 1024);
    __hip_bfloat16* gg1T  = (__hip_bfloat16*)(W + 8 * MB + 320 * 1024);
    __hip_bfloat16* gg2T  = (__hip_bfloat16*)(W + 8 * MB + 384 * 1024);
    float* rcs1  = (float*)(W + 9 * MB);                        // 4 KB
    float* rcs2  = rcs1 + 1024;
    float* invde = rcs2 + 1024;                                 // 512

    // 1. prep: transposes (128x32 tiles) + out-init + invde
    prep_k<<<1309, 256, 0, stream>>>(
        features, fc2_w, fc2_b, g1_w, g2_w, wq, wk, wv, wq2, wk2,
        gg1_w, gg2_w, fc2T, wdT, wvT, g1T, g2T, wd2T, gg1T, gg2T, invde, out);

    // 2. x = features @ fc1_w + fc1_b (fp32 inputs, reg-staged)
    xgemm_k<<<1024, 256, 0, stream>>>(features, fc1_w, fc1_b, xb);

    // 3. t1: d2 = gf2 @ (wq-wk)
    t1_k<<<dim3(16, 32), 256, 0, stream>>>(xb + (size_t)14336 * 1024, wdT, d2b);

    // 4. chain -> e1 + pcs1
    chain_k<<<1024, 256, 0, stream>>>(xb, wd2T, gg1T, gg2T, gg1_b, gg2_b, e1, pcs1);

    // 5-6. t2, t3
    t2_k<<<dim3(16, 32), 256, 0, stream>>>(d2b, g1T, g1_b, t2b);
    t3_k<<<dim3(16, 32), 256, 0, stream>>>(t2b, g2T, g2_b, e2b, pcs2);

    // 7. softmax denominators -> reciprocals
    reduce_k<<<32, dim3(64, 16), 0, stream>>>(pcs1, pcs2, rcs1, rcs2);

    // 8. v-GEMM + res epilogue + out-accum
    vres_k<<<dim3(8, 128), 256, 0, stream>>>(
        xb, wvT, e1, e2b, rcs1, rcs2, invde, features, lpe, fc2T, out);
}

// Round 10
// 286.824 us; speedup vs baseline: 1.0482x; 1.0108x over previous
//
#include <hip/hip_runtime.h>
#include <hip/hip_bf16.h>
#include <math.h>
#include <type_traits>

// Round 10:
//  - vres_k: 512 threads / 8 waves (2x4), wave-tile 64x32 -> acc 32 AGPRs,
//    __launch_bounds__(512,4) -> target 4 waves/SIMD = 16 waves/CU (2x prev).
//    Same BK=64 dbuf + counted vmcnt(4) (4 loads/thread/tile).
//  - t1/t2/t3: triple-buffered BK=32 (2 tiles in flight, vmcnt(4)) -> deeper
//    pipeline at same occupancy.
//  - prep/xgemm/chain/reduce unchanged (named kernels for profile visibility).

typedef __attribute__((ext_vector_type(8))) short short8;
typedef __attribute__((ext_vector_type(4))) float f32x4;
typedef __attribute__((ext_vector_type(4))) float float4v;

#define GLOAD_LDS16(gptr, lptr)                                                 \
    __builtin_amdgcn_global_load_lds(                                           \
        (const __attribute__((address_space(1))) void*)(gptr),                  \
        (__attribute__((address_space(3))) void*)(lptr), 16, 0, 0)

static __device__ __forceinline__ unsigned short f2bf_bits(float v) {
    __hip_bfloat16 h = __float2bfloat16(v);
    return __builtin_bit_cast(unsigned short, h);
}
static __device__ __forceinline__ float bf_bits2f(unsigned short u) {
    return __bfloat162float(__builtin_bit_cast(__hip_bfloat16, u));
}
static __device__ __forceinline__ int swz16(int r, int c16) {
    return (r << 4) + (c16 ^ (r & 7));
}
static __device__ __forceinline__ int swz_elem(int r, int c) {
    return (r << 7) + ((((c << 1) ^ ((r & 7) << 4))) >> 1);
}
static __device__ __forceinline__ int xcd_swz(int bid, int nwg) {
    return (bid & 7) * (nwg >> 3) + (bid >> 3);
}

// ---------------- prep: transposes (128x32/block) + out-init + invde --------
static __device__ void conv_t_dev(const float* __restrict__ A, const float* __restrict__ Bsub,
                                  __hip_bfloat16* __restrict__ Ot, int K, int N,
                                  int bx, int by, int tid, float* t /* [32][33] */)
{
    const int n0 = bx * 32, k0 = by * 128;
    const int tx = tid & 31, ty = tid >> 5;
    const int ksub = (K - k0 < 128) ? (K - k0) / 32 : 4;
    for (int s = 0; s < ksub; ++s) {
        const int kk = k0 + s * 32;
        #pragma unroll
        for (int j = 0; j < 4; ++j) {
            int k = kk + ty + j * 8;
            float v = A[(long)k * N + n0 + tx];
            if (Bsub) v -= Bsub[(long)k * N + n0 + tx];
            t[(ty + j * 8) * 33 + tx] = v;
        }
        __syncthreads();
        #pragma unroll
        for (int j = 0; j < 4; ++j) {
            int n = n0 + ty + j * 8;
            Ot[(long)n * K + kk + tx] = __float2bfloat16(t[tx * 33 + ty + j * 8]);
        }
        __syncthreads();
    }
}

__global__ __launch_bounds__(256) void prep_k(
    const float* __restrict__ features, const float* __restrict__ fc2_w,
    const float* __restrict__ fc2_b, const float* __restrict__ g1_w,
    const float* __restrict__ g2_w, const float* __restrict__ wq,
    const float* __restrict__ wk, const float* __restrict__ wv,
    const float* __restrict__ wq2, const float* __restrict__ wk2,
    const float* __restrict__ gg1_w, const float* __restrict__ gg2_w,
    __hip_bfloat16* __restrict__ fc2T, __hip_bfloat16* __restrict__ wdT,
    __hip_bfloat16* __restrict__ wvT, __hip_bfloat16* __restrict__ g1T,
    __hip_bfloat16* __restrict__ g2T, __hip_bfloat16* __restrict__ wd2T,
    __hip_bfloat16* __restrict__ gg1T, __hip_bfloat16* __restrict__ gg2T,
    float* __restrict__ invde, float* __restrict__ out)
{
    __shared__ float t[32 * 33];
    const int bid = blockIdx.x;
    const int tid = threadIdx.x;

    if (bid == 0) {
        #pragma unroll
        for (int i = 0; i < 2; ++i) {
            int idx = tid + i * 256;
            invde[idx] = exp2f(-9.96578428466209f * (float)idx * (1.f / 512.f));
        }
    } else if (bid < 257) {               // out = features + fc2_b
        const float4v* f4 = (const float4v*)features;
        float4v* o4 = (float4v*)out;
        const float4v* b4 = (const float4v*)fc2_b;
        long base = (long)(bid - 1) * 1024;
        #pragma unroll
        for (int i = 0; i < 4; ++i) {
            long idx = base + tid + i * 256;
            o4[idx] = f4[idx] + b4[idx & 15];
        }
    } else if (bid < 513) {
        int tt = bid - 257;  conv_t_dev(wq, wk, wdT, 1024, 1024, tt & 31, tt >> 5, tid, t);
    } else if (bid < 769) {
        int tt = bid - 513;  conv_t_dev(wv, nullptr, wvT, 1024, 1024, tt & 31, tt >> 5, tid, t);
    } else if (bid < 1025) {
        int tt = bid - 769;  conv_t_dev(g1_w, nullptr, g1T, 1024, 1024, tt & 31, tt >> 5, tid, t);
    } else if (bid < 1281) {
        int tt = bid - 1025; conv_t_dev(g2_w, nullptr, g2T, 1024, 1024, tt & 31, tt >> 5, tid, t);
    } else if (bid < 1297) {
        int tt = bid - 1281; conv_t_dev(fc2_w, nullptr, fc2T, 1024, 64, tt & 1, tt >> 1, tid, t);
    } else if (bid < 1301) {
        int tt = bid - 1297; conv_t_dev(wq2, wk2, wd2T, 128, 128, tt & 3, 0, tid, t);
    } else if (bid < 1305) {
        int tt = bid - 1301; conv_t_dev(gg1_w, nullptr, gg1T, 128, 128, tt & 3, 0, tid, t);
    } else {
        int tt = bid - 1305; conv_t_dev(gg2_w, nullptr, gg2T, 128, 128, tt & 3, 0, tid, t);
    }
}

// ---------------- x-GEMM from fp32 inputs ----------------
__global__ __launch_bounds__(256) void xgemm_k(
    const float* __restrict__ features, const float* __restrict__ fc1_w,
    const float* __restrict__ fc1_b, __hip_bfloat16* __restrict__ xb)
{
    __shared__ __align__(16) char smem[32768];
    unsigned short* As = (unsigned short*)smem;
    unsigned short* Bs = (unsigned short*)(smem + 16384);
    const int tile = blockIdx.x;
    const int tid = threadIdx.x;
    const int bm = (tile >> 3) << 7, bn = (tile & 7) << 7;
    const int wid = tid >> 6, lane = tid & 63;
    const int wm = (wid >> 1) << 6, wn = (wid & 1) << 6;
    const int l15 = lane & 15, kg = lane >> 4;

    #pragma unroll
    for (int i = 0; i < 8; ++i) {
        int idx = i * 256 + tid;
        int r = idx >> 4, c4 = idx & 15;
        float4v f = *(const float4v*)(features + (long)(bm + r) * 64 + c4 * 4);
        unsigned int p0 = f2bf_bits(f[0]) | ((unsigned int)f2bf_bits(f[1]) << 16);
        unsigned int p1 = f2bf_bits(f[2]) | ((unsigned int)f2bf_bits(f[3]) << 16);
        int dst = r * 64 + (((c4 >> 1) ^ (r & 7)) << 3) + (c4 & 1) * 4;
        unsigned int* p = (unsigned int*)&As[dst];
        p[0] = p0; p[1] = p1;
    }
    #pragma unroll
    for (int i = 0; i < 8; ++i) {
        int idx = i * 256 + tid;
        int k = idx >> 5, c4b = idx & 31;
        float4v g = *(const float4v*)(fc1_w + (long)k * 1024 + bn + c4b * 4);
        #pragma unroll
        for (int q = 0; q < 4; ++q) {
            int n = c4b * 4 + q;
            Bs[n * 64 + (((k >> 3) ^ (n & 7)) << 3) + (k & 7)] = f2bf_bits(g[q]);
        }
    }
    __syncthreads();

    f32x4 acc[4][4] = {};
    #pragma unroll
    for (int ks2 = 0; ks2 < 2; ++ks2) {
        const int kslot = ks2 * 4 + kg;
        short8 af[4], bf_[4];
        #pragma unroll
        for (int m = 0; m < 4; ++m) {
            int r = wm + m * 16 + l15;
            af[m] = *(const short8*)&As[r * 64 + ((kslot ^ (r & 7)) << 3)];
        }
        #pragma unroll
        for (int n = 0; n < 4; ++n) {
            int r = wn + n * 16 + l15;
            bf_[n] = *(const short8*)&Bs[r * 64 + ((kslot ^ (r & 7)) << 3)];
        }
        #pragma unroll
        for (int m = 0; m < 4; ++m)
            #pragma unroll
            for (int n = 0; n < 4; ++n)
                acc[m][n] = __builtin_amdgcn_mfma_f32_16x16x32_bf16(
                    af[m], bf_[n], acc[m][n], 0, 0, 0);
    }
    const int rq = kg << 2;
    #pragma unroll
    for (int n = 0; n < 4; ++n) {
        const int col = bn + wn + n * 16 + l15;
        const float bv = fc1_b[col];
        #pragma unroll
        for (int m = 0; m < 4; ++m)
            #pragma unroll
            for (int j = 0; j < 4; ++j)
                xb[(long)(bm + wm + m * 16 + rq + j) * 1024 + col] =
                    __float2bfloat16(acc[m][n][j] + bv);
    }
}

// ------- 64x64 GEMM, BK=32, TRIPLE-buffer (2 tiles in flight) -------
template <int OP, bool CS>
static __device__ void gemm6464_dev(
    const __hip_bfloat16* __restrict__ A, const __hip_bfloat16* __restrict__ Bt,
    const float* __restrict__ bias, __hip_bfloat16* __restrict__ Co,
    float scale, float* __restrict__ pcs, int swz, int tid, char* smem)
{
    const int wid = tid >> 6, lane = tid & 63;
    const int bm = (swz >> 4) << 6, bn = (swz & 15) << 6;
    const int wm = (wid >> 1) << 5, wn = (wid & 1) << 5;
    f32x4 acc[2][2] = {};
    const int l15 = lane & 15, kg = lane >> 4;
    const int rS = tid >> 2;
    const int c4s = (tid & 3) ^ ((rS >> 1) & 3);

#define G66_STAGE(b, k0)                                                        \
    { char* base = smem + (b) * 8192;                                           \
      GLOAD_LDS16(A + (long)(bm + rS) * 1024 + (k0) + c4s * 8,                  \
                  base + (wid << 6) * 16);                                      \
      GLOAD_LDS16(Bt + (long)(bn + rS) * 1024 + (k0) + c4s * 8,                 \
                  base + 4096 + (wid << 6) * 16); }

    G66_STAGE(0, 0);
    G66_STAGE(1, 32);
    int cur = 0, nxt = 2;
    for (int kt = 0; kt < 32; ++kt) {
        if (kt < 30) {
            G66_STAGE(nxt, (kt + 2) * 32);
            asm volatile("s_waitcnt vmcnt(4)" ::: "memory");
        } else if (kt == 30) {
            asm volatile("s_waitcnt vmcnt(2)" ::: "memory");
        } else {
            asm volatile("s_waitcnt vmcnt(0)" ::: "memory");
        }
        __builtin_amdgcn_s_barrier();
        __builtin_amdgcn_sched_barrier(0);
        const char* AsB = smem + cur * 8192;
        const char* BsB = AsB + 4096;
        short8 af[2], bf_[2];
        #pragma unroll
        for (int m = 0; m < 2; ++m) {
            const int R = wm + m * 16 + l15;
            af[m] = *(const short8*)(AsB + R * 64 + ((kg ^ ((R >> 1) & 3)) << 4));
        }
        #pragma unroll
        for (int n = 0; n < 2; ++n) {
            const int R = wn + n * 16 + l15;
            bf_[n] = *(const short8*)(BsB + R * 64 + ((kg ^ ((R >> 1) & 3)) << 4));
        }
        __builtin_amdgcn_s_setprio(1);
        #pragma unroll
        for (int m = 0; m < 2; ++m)
            #pragma unroll
            for (int n = 0; n < 2; ++n)
                acc[m][n] = __builtin_amdgcn_mfma_f32_16x16x32_bf16(
                    af[m], bf_[n], acc[m][n], 0, 0, 0);
        __builtin_amdgcn_s_setprio(0);
        __builtin_amdgcn_s_barrier();
        cur = (cur == 2) ? 0 : cur + 1;
        nxt = (nxt == 2) ? 0 : nxt + 1;
    }
#undef G66_STAGE

    const int rq = kg << 2;
    float csum[2];
    #pragma unroll
    for (int n = 0; n < 2; ++n) {
        const int col = bn + wn + n * 16 + l15;
        const float bv = bias ? bias[col] : 0.f;
        csum[n] = 0.f;
        #pragma unroll
        for (int m = 0; m < 2; ++m) {
            #pragma unroll
            for (int j = 0; j < 4; ++j) {
                const int row = bm + wm + m * 16 + rq + j;
                float cv = acc[m][n][j] + bv;
                if (OP == 1) cv = fmaxf(cv, 0.f);
                if (OP == 2) cv = __expf(cv * scale);
                if (CS) csum[n] += cv;
                Co[(long)row * 1024 + col] = __float2bfloat16(cv);
            }
        }
    }
    if (CS) {
        __syncthreads();
        float* ps = (float*)smem;
        const int slot = ((wid >> 1) << 2) | kg;
        #pragma unroll
        for (int n = 0; n < 2; ++n)
            ps[(wn + n * 16 + l15) * 8 + slot] = csum[n];
        __syncthreads();
        if (tid < 64) {
            float s = 0.f;
            #pragma unroll
            for (int q = 0; q < 8; ++q) s += ps[tid * 8 + q];
            pcs[(long)(swz >> 4) * 1024 + bn + tid] = s;
        }
    }
}

__global__ __launch_bounds__(256) void t1_k(
    const __hip_bfloat16* __restrict__ A, const __hip_bfloat16* __restrict__ Bt,
    __hip_bfloat16* __restrict__ Co)
{
    __shared__ __align__(16) char smem[24576];
    const int swz = xcd_swz(blockIdx.y * gridDim.x + blockIdx.x, gridDim.x * gridDim.y);
    gemm6464_dev<0, false>(A, Bt, nullptr, Co, 0.f, nullptr, swz, threadIdx.x, smem);
}
__global__ __launch_bounds__(256) void t2_k(
    const __hip_bfloat16* __restrict__ A, const __hip_bfloat16* __restrict__ Bt,
    const float* __restrict__ bias, __hip_bfloat16* __restrict__ Co)
{
    __shared__ __align__(16) char smem[24576];
    const int swz = xcd_swz(blockIdx.y * gridDim.x + blockIdx.x, gridDim.x * gridDim.y);
    gemm6464_dev<1, false>(A, Bt, bias, Co, 0.f, nullptr, swz, threadIdx.x, smem);
}
__global__ __launch_bounds__(256) void t3_k(
    const __hip_bfloat16* __restrict__ A, const __hip_bfloat16* __restrict__ Bt,
    const float* __restrict__ bias, __hip_bfloat16* __restrict__ Co,
    float* __restrict__ pcs)
{
    __shared__ __align__(16) char smem[24576];
    const int swz = xcd_swz(blockIdx.y * gridDim.x + blockIdx.x, gridDim.x * gridDim.y);
    gemm6464_dev<2, true>(A, Bt, bias, Co, 0.03125f, pcs, swz, threadIdx.x, smem);
}

// ---------------- fused group-MLP chain ----------------
__global__ __launch_bounds__(256) void chain_k(
    const __hip_bfloat16* __restrict__ xb,
    const __hip_bfloat16* __restrict__ w1T,
    const __hip_bfloat16* __restrict__ w2T,
    const __hip_bfloat16* __restrict__ w3T,
    const float* __restrict__ b2, const float* __restrict__ b3,
    __hip_bfloat16* __restrict__ e1, float* __restrict__ pcs1)
{
    __shared__ __align__(16) char smem[65536];
    unsigned short* act = (unsigned short*)smem;
    unsigned short* Wb  = (unsigned short*)(smem + 32768);
    const int tid = threadIdx.x;
    const int wid = tid >> 6, lane = tid & 63;
    const int wm = (wid >> 1) << 6, wn = (wid & 1) << 6;
    const int tileIdx = blockIdx.x;
    const long tile = (long)tileIdx * (128 * 128);

    #pragma unroll
    for (int i = 0; i < 8; ++i) {
        int L = i * 256 + wid * 64 + lane;
        int r = L >> 4, c16o = (L & 15) ^ (r & 7);
        GLOAD_LDS16(xb + tile + r * 128 + c16o * 8,
                    (char*)act + (i * 256 + wid * 64) * 16);
        GLOAD_LDS16(w1T + r * 128 + c16o * 8,
                    (char*)Wb + (i * 256 + wid * 64) * 16);
    }
    __syncthreads();

    f32x4 acc[4][4];
    const int rq = (lane >> 4) << 2;

#define CHAIN_ZERO()                                                            \
    _Pragma("unroll") for (int m = 0; m < 4; ++m)                               \
        _Pragma("unroll") for (int n = 0; n < 4; ++n)                           \
            acc[m][n] = (f32x4){0.f, 0.f, 0.f, 0.f};

#define CHAIN_MM()                                                              \
    _Pragma("unroll") for (int ks = 0; ks < 4; ++ks) {                          \
        short8 af[4], bfv[4];                                                   \
        const int kc = ks * 4 + (lane >> 4);                                    \
        _Pragma("unroll") for (int m = 0; m < 4; ++m) {                         \
            int r = wm + m * 16 + (lane & 15);                                  \
            af[m] = *(const short8*)((const char*)act + swz16(r, kc) * 16);     \
        }                                                                       \
        _Pragma("unroll") for (int n = 0; n < 4; ++n) {                         \
            int r = wn + n * 16 + (lane & 15);                                  \
            bfv[n] = *(const short8*)((const char*)Wb + swz16(r, kc) * 16);     \
        }                                                                       \
        _Pragma("unroll") for (int m = 0; m < 4; ++m)                           \
            _Pragma("unroll") for (int n = 0; n < 4; ++n)                       \
                acc[m][n] = __builtin_amdgcn_mfma_f32_16x16x32_bf16(            \
                    af[m], bfv[n], acc[m][n], 0, 0, 0);                         \
    }

#define STAGE_W(wptr)                                                           \
    _Pragma("unroll") for (int i = 0; i < 8; ++i) {                             \
        int L = i * 256 + wid * 64 + lane;                                      \
        int r = L >> 4, c16o = (L & 15) ^ (r & 7);                              \
        GLOAD_LDS16((wptr) + r * 128 + c16o * 8,                                \
                    (char*)Wb + (i * 256 + wid * 64) * 16);                     \
    }

    CHAIN_ZERO(); CHAIN_MM();
    __syncthreads();
    STAGE_W(w2T);
    #pragma unroll
    for (int m = 0; m < 4; ++m)
        #pragma unroll
        for (int n = 0; n < 4; ++n)
            #pragma unroll
            for (int j = 0; j < 4; ++j) {
                int row = wm + m * 16 + rq + j, col = wn + n * 16 + (lane & 15);
                act[swz_elem(row, col)] = f2bf_bits(acc[m][n][j]);
            }
    __syncthreads();

    CHAIN_ZERO(); CHAIN_MM();
    __syncthreads();
    STAGE_W(w3T);
    {
        float bv[4];
        #pragma unroll
        for (int n = 0; n < 4; ++n) bv[n] = b2[wn + n * 16 + (lane & 15)];
        #pragma unroll
        for (int m = 0; m < 4; ++m)
            #pragma unroll
            for (int n = 0; n < 4; ++n)
                #pragma unroll
                for (int j = 0; j < 4; ++j) {
                    int row = wm + m * 16 + rq + j, col = wn + n * 16 + (lane & 15);
                    act[swz_elem(row, col)] = f2bf_bits(fmaxf(acc[m][n][j] + bv[n], 0.f));
                }
    }
    __syncthreads();

    CHAIN_ZERO(); CHAIN_MM();
    __syncthreads();
    {
        float bv[4];
        #pragma unroll
        for (int n = 0; n < 4; ++n) bv[n] = b3[wn + n * 16 + (lane & 15)];
        #pragma unroll
        for (int m = 0; m < 4; ++m)
            #pragma unroll
            for (int n = 0; n < 4; ++n)
                #pragma unroll
                for (int j = 0; j < 4; ++j) {
                    int row = wm + m * 16 + rq + j, col = wn + n * 16 + (lane & 15);
                    float ev = __expf((acc[m][n][j] + bv[n]) * 0.08838834764831845f);
                    act[swz_elem(row, col)] = f2bf_bits(ev);
                }
    }
    __syncthreads();

    #pragma unroll
    for (int i = 0; i < 8; ++i) {
        int idx = i * 256 + tid;
        int r = idx >> 4, c16o = idx & 15;
        short8 vd = *(const short8*)((const char*)act + swz16(r, c16o) * 16);
        *(short8*)((__hip_bfloat16*)e1 + tile + r * 128 + c16o * 8) = vd;
    }
    #pragma unroll
    for (int i = 0; i < 4; ++i) {
        int p = i * 256 + tid;
        int g = p >> 7, c = p & 127;
        float s = 0.f;
        #pragma unroll
        for (int t16 = 0; t16 < 16; ++t16) {
            int r = t16 * 8 + g;
            s += bf_bits2f(act[swz_elem(r, c)]);
        }
        pcs1[(long)tileIdx * 1024 + p] = s;
    }
#undef CHAIN_ZERO
#undef CHAIN_MM
#undef STAGE_W
}

// reduce: blocks 0-15 -> rcs1, 16-31 -> rcs2
__global__ __launch_bounds__(1024) void reduce_k(
    const float* __restrict__ pcs1, const float* __restrict__ pcs2,
    float* __restrict__ rcs1, float* __restrict__ rcs2)
{
    __shared__ float red[16][64];
    const int tx = threadIdx.x, ty = threadIdx.y;
    if (blockIdx.x < 16) {
        const int col = blockIdx.x * 64 + tx;
        float s = 0.f;
        for (int p = ty; p < 1024; p += 16) s += pcs1[(long)p * 1024 + col];
        red[ty][tx] = s;
        __syncthreads();
        if (ty == 0) {
            float t = 0.f;
            #pragma unroll
            for (int q = 0; q < 16; ++q) t += red[q][tx];
            rcs1[col] = 1.f / t;
        }
    } else {
        const int col = (blockIdx.x - 16) * 64 + tx;
        float s = 0.f;
        for (int p = ty; p < 32; p += 16) s += pcs2[(long)p * 1024 + col];
        red[ty][tx] = s;
        __syncthreads();
        if (ty == 0) {
            float t = 0.f;
            #pragma unroll
            for (int q = 0; q < 16; ++q) t += red[q][tx];
            rcs2[col] = 1.f / t;
        }
    }
}

// ---- v-GEMM: 512 threads / 8 waves (2x4), BK=64 dbuf, vmcnt(4) ----
__global__ __launch_bounds__(512, 4) void vres_k(
    const __hip_bfloat16* __restrict__ A, const __hip_bfloat16* __restrict__ Bt,
    const __hip_bfloat16* __restrict__ e1, const __hip_bfloat16* __restrict__ e2,
    const float* __restrict__ rcs1, const float* __restrict__ rcs2,
    const float* __restrict__ invde, const float* __restrict__ feats,
    const float* __restrict__ lpe, const __hip_bfloat16* __restrict__ fc2T,
    float* __restrict__ out)
{
    __shared__ __align__(16) char smem[65536];            // 2x(As 16K + Bs 16K)
    unsigned short* st = (unsigned short*)smem;           // [128][136] epilogue union

    const int tid = threadIdx.x;                          // 0..511
    const int wid = tid >> 6;                             // 0..7
    const int lane = tid & 63;
    const int swz = xcd_swz(blockIdx.y * gridDim.x + blockIdx.x, gridDim.x * gridDim.y);
    const int bm = (swz >> 3) << 7, bn = (swz & 7) << 7;
    const int wm = (wid >> 2) << 6;                       // 0 or 64
    const int wn = (wid & 3) << 5;                        // 0,32,64,96

    f32x4 acc[4][2] = {};                                 // wave-tile 64x32 -> 32 AGPRs
    const int l15 = lane & 15;
    const int kg = lane >> 4;
    const int arow = wm + l15;
    const int brow = wn + l15;

    // staging: 2 chunks/thread/matrix; chunk idx = i*512+tid, r = idx>>3, c8 = idx&7
#define VR_STAGE(b, k0)                                                         \
    { char* base = smem + (b) * 32768;                                          \
      _Pragma("unroll") for (int i = 0; i < 2; ++i) {                           \
        const int idx = i * 512 + tid;                                          \
        const int r = idx >> 3;                                                 \
        const int c8s = (idx & 7) ^ (r & 7);                                    \
        GLOAD_LDS16(A + (long)(bm + r) * 1024 + (k0) + c8s * 8,                 \
                    base + (i * 512 + wid * 64) * 16);                          \
        GLOAD_LDS16(Bt + (long)(bn + r) * 1024 + (k0) + c8s * 8,                \
                    base + 16384 + (i * 512 + wid * 64) * 16); } }

    VR_STAGE(0, 0);
    #pragma unroll 2
    for (int kt = 0; kt < 16; ++kt) {
        if (kt < 15) {
            VR_STAGE((kt + 1) & 1, (kt + 1) * 64);
            asm volatile("s_waitcnt vmcnt(4)" ::: "memory");
        } else {
            asm volatile("s_waitcnt vmcnt(0)" ::: "memory");
        }
        __builtin_amdgcn_s_barrier();
        __builtin_amdgcn_sched_barrier(0);
        const __hip_bfloat16* As = (const __hip_bfloat16*)(smem + (kt & 1) * 32768);
        const __hip_bfloat16* Bs = (const __hip_bfloat16*)(smem + (kt & 1) * 32768 + 16384);
        __builtin_amdgcn_s_setprio(1);
        #pragma unroll
        for (int ks2 = 0; ks2 < 2; ++ks2) {
            const int kslot = ks2 * 4 + kg;
            short8 af[4], bf_[2];
            #pragma unroll
            for (int m = 0; m < 4; ++m) {
                const int r = arow + m * 16;
                af[m] = *(const short8*)(As + (r * 8 + (kslot ^ (r & 7))) * 8);
            }
            #pragma unroll
            for (int n = 0; n < 2; ++n) {
                const int r = brow + n * 16;
                bf_[n] = *(const short8*)(Bs + (r * 8 + (kslot ^ (r & 7))) * 8);
            }
            #pragma unroll
            for (int m = 0; m < 4; ++m)
                #pragma unroll
                for (int n = 0; n < 2; ++n)
                    acc[m][n] = __builtin_amdgcn_mfma_f32_16x16x32_bf16(
                        af[m], bf_[n], acc[m][n], 0, 0, 0);
        }
        __builtin_amdgcn_s_setprio(0);
        __builtin_amdgcn_s_barrier();
    }
#undef VR_STAGE

    // v tile -> st (bf16); waves cover disjoint 64x32 sub-tiles
    const int rq = kg << 2;
    #pragma unroll
    for (int m = 0; m < 4; ++m)
        #pragma unroll
        for (int n = 0; n < 2; ++n)
            #pragma unroll
            for (int j = 0; j < 4; ++j)
                st[(wm + m * 16 + rq + j) * 136 + wn + n * 16 + l15] =
                    f2bf_bits(acc[m][n][j]);
    __syncthreads();

    // res = (e1*rcs1 + e2*rcs2) * (v + pe) -> st in place (vectorized)
    const float lp = lpe[0];
    #pragma unroll
    for (int p = 0; p < 2; ++p) {
        const int r = p * 64 + (tid >> 3);
        const int cc = (tid & 7) << 4;
        const int grow = bm + r;
        const float angs = 100.f * feats[(long)grow * 64];
        const long goff = (long)grow * 1024 + bn + cc;
        const long goff2 = (long)(grow & 2047) * 1024 + bn + cc;
        short8 ev1[2], ev2[2], sv[2];
        ev1[0] = *(const short8*)((const unsigned short*)e1 + goff);
        ev1[1] = *(const short8*)((const unsigned short*)e1 + goff + 8);
        ev2[0] = *(const short8*)((const unsigned short*)e2 + goff2);
        ev2[1] = *(const short8*)((const unsigned short*)e2 + goff2 + 8);
        sv[0] = *(const short8*)&st[r * 136 + cc];
        sv[1] = *(const short8*)&st[r * 136 + cc + 8];
        unsigned short ov[16];
        #pragma unroll
        for (int q = 0; q < 16; ++q) {
            const int h = bn + cc + q;
            const float ang = angs * invde[h & 511];
            const float tr = (h < 512) ? __sinf(ang) : __cosf(ang);
            const float a = bf_bits2f((unsigned short)ev1[q >> 3][q & 7]) * rcs1[h] +
                            bf_bits2f((unsigned short)ev2[q >> 3][q & 7]) * rcs2[h];
            const float vv = bf_bits2f((unsigned short)sv[q >> 3][q & 7]);
            ov[q] = f2bf_bits(a * (vv + (tr + lp) * lp));
        }
        *(short8*)&st[r * 136 + cc] = *(short8*)&ov[0];
        *(short8*)&st[r * 136 + cc + 8] = *(short8*)&ov[8];
    }
    __syncthreads();

    // out[bm:+128, :] += res_tile @ fc2_w[bn:+128, :]  (16 rows per wave)
    {
        const int wmO = wid << 4;
        f32x4 aco[4] = {};
        #pragma unroll
        for (int ks = 0; ks < 4; ++ks) {
            short8 afo = *(const short8*)&st[(wmO + l15) * 136 + ks * 32 + kg * 8];
            #pragma unroll
            for (int n = 0; n < 4; ++n) {
                short8 bfo = *(const short8*)((const unsigned short*)fc2T +
                                              (long)(n * 16 + l15) * 1024 + bn + ks * 32 + kg * 8);
                aco[n] = __builtin_amdgcn_mfma_f32_16x16x32_bf16(afo, bfo, aco[n], 0, 0, 0);
            }
        }
        #pragma unroll
        for (int n = 0; n < 4; ++n)
            #pragma unroll
            for (int j = 0; j < 4; ++j) {
                const int row = bm + wmO + rq + j;
                atomicAdd(&out[(long)row * 64 + n * 16 + l15], aco[n][j]);
            }
    }
}

extern "C" void kernel_launch(void* const* d_in, const int* in_sizes, int n_in,
                              void* d_out, int out_size, void* d_ws, size_t ws_size,
                              hipStream_t stream) {
    const float* features = (const float*)d_in[0];
    const float* fc1_w = (const float*)d_in[1];
    const float* fc1_b = (const float*)d_in[2];
    const float* fc2_w = (const float*)d_in[3];
    const float* fc2_b = (const float*)d_in[4];
    const float* g1_w = (const float*)d_in[5];
    const float* g1_b = (const float*)d_in[6];
    const float* g2_w = (const float*)d_in[7];
    const float* g2_b = (const float*)d_in[8];
    const float* gg1_w = (const float*)d_in[9];
    const float* gg1_b = (const float*)d_in[10];
    const float* gg2_w = (const float*)d_in[11];
    const float* gg2_b = (const float*)d_in[12];
    const float* wq = (const float*)d_in[13];
    const float* wk = (const float*)d_in[14];
    const float* wv = (const float*)d_in[15];
    const float* wq2 = (const float*)d_in[16];
    const float* wk2 = (const float*)d_in[17];
    const float* lpe = (const float*)d_in[18];
    float* out = (float*)d_out;

    char* ws = (char*)d_ws;
    const size_t MB = 1024ull * 1024ull;
    __hip_bfloat16* xb   = (__hip_bfloat16*)ws;                 // 32 MB
    __hip_bfloat16* e1   = (__hip_bfloat16*)(ws + 32 * MB);     // 32 MB
    __hip_bfloat16* d2b  = (__hip_bfloat16*)(ws + 64 * MB);     // 4 MB
    __hip_bfloat16* t2b  = (__hip_bfloat16*)(ws + 68 * MB);     // 4 MB
    __hip_bfloat16* e2b  = (__hip_bfloat16*)(ws + 72 * MB);     // 4 MB
    float*          pcs1 = (float*)(ws + 76 * MB);              // 4 MB
    float*          pcs2 = (float*)(ws + 80 * MB);              // 128 KB
    char* W = ws + 81 * MB;
    __hip_bfloat16* wdT   = (__hip_bfloat16*)W;                 // 2 MB
    __hip_bfloat16* wvT   = (__hip_bfloat16*)(W + 2 * MB);      // 2 MB
    __hip_bfloat16* g1T   = (__hip_bfloat16*)(W + 4 * MB);      // 2 MB
    __hip_bfloat16* g2T   = (__hip_bfloat16*)(W + 6 * MB);      // 2 MB
    __hip_bfloat16* fc2T  = (__hip_bfloat16*)(W + 8 * MB);      // 128 KB
    __hip_bfloat16* wd2T  = (__hip_bfloat16*)(W + 8 * MB + 256 * 1024);
    __hip_bfloat16* gg1T  = (__hip_bfloat16*)(W + 8 * MB + 320 * 1024);
    __hip_bfloat16* gg2T  = (__hip_bfloat16*)(W + 8 * MB + 384 * 1024);
    float* rcs1  = (float*)(W + 9 * MB);                        // 4 KB
    float* rcs2  = rcs1 + 1024;
    float* invde = rcs2 + 1024;                                 // 512

    // 1. prep: transposes + out-init + invde
    prep_k<<<1309, 256, 0, stream>>>(
        features, fc2_w, fc2_b, g1_w, g2_w, wq, wk, wv, wq2, wk2,
        gg1_w, gg2_w, fc2T, wdT, wvT, g1T, g2T, wd2T, gg1T, gg2T, invde, out);

    // 2. x = features @ fc1_w + fc1_b
    xgemm_k<<<1024, 256, 0, stream>>>(features, fc1_w, fc1_b, xb);

    // 3. t1: d2 = gf2 @ (wq-wk)
    t1_k<<<dim3(16, 32), 256, 0, stream>>>(xb + (size_t)14336 * 1024, wdT, d2b);

    // 4. chain -> e1 + pcs1
    chain_k<<<1024, 256, 0, stream>>>(xb, wd2T, gg1T, gg2T, gg1_b, gg2_b, e1, pcs1);

    // 5-6. t2, t3
    t2_k<<<dim3(16, 32), 256, 0, stream>>>(d2b, g1T, g1_b, t2b);
    t3_k<<<dim3(16, 32), 256, 0, stream>>>(t2b, g2T, g2_b, e2b, pcs2);

    // 7. softmax denominators -> reciprocals
    reduce_k<<<32, dim3(64, 16), 0, stream>>>(pcs1, pcs2, rcs1, rcs2);

    // 8. v-GEMM + res epilogue + out-accum (512 threads / 8 waves)
    vres_k<<<dim3(8, 128), 512, 0, stream>>>(
        xb, wvT, e1, e2b, rcs1, rcs2, invde, features, lpe, fc2T, out);
}